// Round 3
// baseline (604.232 us; speedup 1.0000x reference)
//
#include <hip/hip_runtime.h>
#include <hip/hip_bf16.h>
#include <stdint.h>
#include <stddef.h>

// MoBA forward, MI355X.
//  split hs -> bf16 hi/lo; transpose-cast W's -> B^T bf16
//  GEMM1 (bf16 MFMA, LDS-staged coalesced bf16 epilogue): qkv[2048][6144]
//  fp32 gate path: hsmean -> kg (fp32) -> wg = Wq_h @ kg_h (fp32)
//    gate partials = bf16x3 MFMA split 6 ways (3 phases x 2 K-halves), 128^2 tiles
//  gate_topk: sums 6 partials, rank-based top-8 -> 32-bit block mask
//  attn v4: block-sparse flash, 1 WAVE per (h, 16-row q-chunk), NO K/V staging
//    (K/V are L2-resident per-XCD: 2 heads/XCD remap). No barriers at all.
//    bf16 P via per-wave LDS slab; lacc row-sum via ones-MFMA; defer-max.
//  GEMM2: o @ Wo on 128^2 tiles -> d_out fp32

using bh = __bf16;
typedef __bf16 bhx8 __attribute__((ext_vector_type(8)));
typedef __bf16 bhx4 __attribute__((ext_vector_type(4)));
typedef float  f32x4 __attribute__((ext_vector_type(4)));

#define SEQ   2048
#define HIDN  2048
#define NHEAD 16
#define HDIM  128
#define NBLK  32
#define BLKSZ 64
#define NQKV  6144
#define NGATE 512   // NBLK*NHEAD gate columns
#define LDK   72    // padded LDS row stride for GEMM K-tiles (64+8)
#define LDC   136   // C-tile epilogue stride: 272 B/row = 16B-aligned, 2-way banks (free)
#define PSTRIDE ((size_t)SEQ * NGATE)   // gate partial plane stride

// ---------------- split fp32 -> bf16 hi + lo ----------------
__global__ __launch_bounds__(256) void split_f32(const float* __restrict__ in,
                                                 bh* __restrict__ hi, bh* __restrict__ lo, int n) {
  int i = (blockIdx.x * 256 + threadIdx.x) * 4;
  if (i >= n) return;
  float4 v = *(const float4*)(in + i);
  bhx4 h4, l4;
  float vv[4] = {v.x, v.y, v.z, v.w};
#pragma unroll
  for (int e = 0; e < 4; e++) {
    bh h = (bh)vv[e];
    h4[e] = h;
    l4[e] = (bh)(vv[e] - (float)h);
  }
  *(bhx4*)(hi + i) = h4;
  *(bhx4*)(lo + i) = l4;
}

// ---------------- transpose + cast: in[R][C] fp32 -> out[C][R] bf16 ----------------
__global__ __launch_bounds__(256) void transpose_cast(const float* __restrict__ in,
                                                      bh* __restrict__ out, int R, int C) {
  __shared__ float tile[32][33];
  int tx = threadIdx.x, ty = threadIdx.y;
  int c0 = blockIdx.x * 32, r0 = blockIdx.y * 32;
#pragma unroll
  for (int i = 0; i < 4; i++)
    tile[ty + i * 8][tx] = in[(size_t)(r0 + ty + i * 8) * C + c0 + tx];
  __syncthreads();
#pragma unroll
  for (int i = 0; i < 4; i++)
    out[(size_t)(c0 + ty + i * 8) * R + r0 + tx] = (bh)tile[tx][ty + i * 8];
}

// ---------------- bf16 MFMA GEMM 128x128, B^T layout, coalesced bf16 epilogue ----------------
// C[M][N] = A[M][K] * BT[N][K]^T ; bf16 out via LDS restage + uint4 stores.
__global__ __launch_bounds__(256) void gemm_bt(const bh* __restrict__ A, const bh* __restrict__ BT,
                                               bh* __restrict__ Cb, int M, int N, int K) {
  __shared__ __align__(16) bh smem[2 * 128 * LDK];   // 36 KB; reused as 128xLDC C-tile (34 KB)
  bh* As = smem;
  bh* Bs = smem + 128 * LDK;
  const int t = threadIdx.x;
  const int L = t & 63, w = t >> 6;
  const int wm = w & 1, wn = w >> 1;
  const int quad = L >> 4, lo = L & 15;
  const int m0 = blockIdx.y * 128, n0 = blockIdx.x * 128;

  f32x4 acc[4][4];
#pragma unroll
  for (int i = 0; i < 4; i++)
#pragma unroll
    for (int j = 0; j < 4; j++) acc[i][j] = (f32x4){0.f, 0.f, 0.f, 0.f};

  for (int k0 = 0; k0 < K; k0 += 64) {
#pragma unroll
    for (int c = 0; c < 4; c++) {
      int i = c * 256 + t;
      int row = i >> 3, cg = i & 7;
      *(uint4*)&As[row * LDK + cg * 8] = *(const uint4*)(A + (size_t)(m0 + row) * K + k0 + cg * 8);
      *(uint4*)&Bs[row * LDK + cg * 8] = *(const uint4*)(BT + (size_t)(n0 + row) * K + k0 + cg * 8);
    }
    __syncthreads();
#pragma unroll
    for (int ks = 0; ks < 2; ks++) {
      bhx8 af[4], bf_[4];
#pragma unroll
      for (int i = 0; i < 4; i++)
        af[i] = *(const bhx8*)&As[(wm * 64 + i * 16 + lo) * LDK + ks * 32 + quad * 8];
#pragma unroll
      for (int j = 0; j < 4; j++)
        bf_[j] = *(const bhx8*)&Bs[(wn * 64 + j * 16 + lo) * LDK + ks * 32 + quad * 8];
#pragma unroll
      for (int i = 0; i < 4; i++)
#pragma unroll
        for (int j = 0; j < 4; j++)
          acc[i][j] = __builtin_amdgcn_mfma_f32_16x16x32_bf16(af[i], bf_[j], acc[i][j], 0, 0, 0);
    }
    __syncthreads();
  }

  // epilogue: scatter acc -> LDS C-tile, then fully-coalesced 16B global stores
  bh* Cs = smem;
#pragma unroll
  for (int i = 0; i < 4; i++)
#pragma unroll
    for (int j = 0; j < 4; j++)
#pragma unroll
      for (int r = 0; r < 4; r++)
        Cs[(wm * 64 + i * 16 + quad * 4 + r) * LDC + wn * 64 + j * 16 + lo] = (bh)acc[i][j][r];
  __syncthreads();
#pragma unroll
  for (int it = 0; it < 8; it++) {
    int idx = it * 256 + t;                 // 2048 chunks: 128 rows x 16
    int row = idx >> 4, cg = idx & 15;
    *(uint4*)(Cb + (size_t)(m0 + row) * N + n0 + cg * 8) = *(const uint4*)&Cs[row * LDC + cg * 8];
  }
}

// ---------------- bf16 MFMA GEMM 128x128, B^T layout, fp32 out (o-projection) ----------------
__global__ __launch_bounds__(256) void gemm_bt128f(const bh* __restrict__ A, const bh* __restrict__ BT,
                                                   float* __restrict__ Cf, int M, int N, int K) {
  __shared__ __align__(16) bh smem[2 * 128 * LDK];
  bh* As = smem;
  bh* Bs = smem + 128 * LDK;
  const int t = threadIdx.x;
  const int L = t & 63, w = t >> 6;
  const int wm = w & 1, wn = w >> 1;
  const int quad = L >> 4, lo = L & 15;
  const int m0 = blockIdx.y * 128, n0 = blockIdx.x * 128;

  f32x4 acc[4][4];
#pragma unroll
  for (int i = 0; i < 4; i++)
#pragma unroll
    for (int j = 0; j < 4; j++) acc[i][j] = (f32x4){0.f, 0.f, 0.f, 0.f};

  for (int k0 = 0; k0 < K; k0 += 64) {
#pragma unroll
    for (int c = 0; c < 4; c++) {
      int i = c * 256 + t;
      int row = i >> 3, cg = i & 7;
      *(uint4*)&As[row * LDK + cg * 8] = *(const uint4*)(A + (size_t)(m0 + row) * K + k0 + cg * 8);
      *(uint4*)&Bs[row * LDK + cg * 8] = *(const uint4*)(BT + (size_t)(n0 + row) * K + k0 + cg * 8);
    }
    __syncthreads();
#pragma unroll
    for (int ks = 0; ks < 2; ks++) {
      bhx8 af[4], bf_[4];
#pragma unroll
      for (int i = 0; i < 4; i++)
        af[i] = *(const bhx8*)&As[(wm * 64 + i * 16 + lo) * LDK + ks * 32 + quad * 8];
#pragma unroll
      for (int j = 0; j < 4; j++)
        bf_[j] = *(const bhx8*)&Bs[(wn * 64 + j * 16 + lo) * LDK + ks * 32 + quad * 8];
#pragma unroll
      for (int i = 0; i < 4; i++)
#pragma unroll
        for (int j = 0; j < 4; j++)
          acc[i][j] = __builtin_amdgcn_mfma_f32_16x16x32_bf16(af[i], bf_[j], acc[i][j], 0, 0, 0);
    }
    __syncthreads();
  }

  // fp32 stores: 16 lanes x 4 B = full 64 B sectors per quad-row (no amplification)
#pragma unroll
  for (int i = 0; i < 4; i++)
#pragma unroll
    for (int j = 0; j < 4; j++)
#pragma unroll
      for (int r = 0; r < 4; r++) {
        int row = m0 + wm * 64 + i * 16 + quad * 4 + r;
        int col = n0 + wn * 64 + j * 16 + lo;
        Cf[(size_t)row * N + col] = acc[i][j][r];
      }
}

// ---------------- gate GEMM, 6-way split, 128^2 tiles ----------------
// z = phase*2 + khalf; phase 0: hi@wgh, 1: lo@wgh, 2: hi@wgl; K=1024 each.
__global__ __launch_bounds__(256) void gemm_gate_split(const bh* __restrict__ hs_hi,
                                                       const bh* __restrict__ hs_lo,
                                                       const bh* __restrict__ wg_hi,
                                                       const bh* __restrict__ wg_lo,
                                                       float* __restrict__ part) {
  __shared__ __align__(16) bh smem[2 * 128 * LDK];
  bh* As = smem;
  bh* Bs = smem + 128 * LDK;
  const int t = threadIdx.x;
  const int L = t & 63, w = t >> 6;
  const int wm = w & 1, wn = w >> 1;
  const int quad = L >> 4, lo = L & 15;
  const int m0 = blockIdx.y * 128, n0 = blockIdx.x * 128;
  const int z = blockIdx.z;
  const bh* Ap = ((z >> 1) == 1) ? hs_lo : hs_hi;
  const bh* Bp = ((z >> 1) == 2) ? wg_lo : wg_hi;
  const int kb = (z & 1) * 1024;

  f32x4 acc[4][4];
#pragma unroll
  for (int i = 0; i < 4; i++)
#pragma unroll
    for (int j = 0; j < 4; j++) acc[i][j] = (f32x4){0.f, 0.f, 0.f, 0.f};

  for (int k0 = 0; k0 < 1024; k0 += 64) {
#pragma unroll
    for (int c = 0; c < 4; c++) {
      int i = c * 256 + t;
      int row = i >> 3, cg = i & 7;
      *(uint4*)&As[row * LDK + cg * 8] = *(const uint4*)(Ap + (size_t)(m0 + row) * HIDN + kb + k0 + cg * 8);
      *(uint4*)&Bs[row * LDK + cg * 8] = *(const uint4*)(Bp + (size_t)(n0 + row) * HIDN + kb + k0 + cg * 8);
    }
    __syncthreads();
#pragma unroll
    for (int ks = 0; ks < 2; ks++) {
      bhx8 af[4], bf_[4];
#pragma unroll
      for (int i = 0; i < 4; i++)
        af[i] = *(const bhx8*)&As[(wm * 64 + i * 16 + lo) * LDK + ks * 32 + quad * 8];
#pragma unroll
      for (int j = 0; j < 4; j++)
        bf_[j] = *(const bhx8*)&Bs[(wn * 64 + j * 16 + lo) * LDK + ks * 32 + quad * 8];
#pragma unroll
      for (int i = 0; i < 4; i++)
#pragma unroll
        for (int j = 0; j < 4; j++)
          acc[i][j] = __builtin_amdgcn_mfma_f32_16x16x32_bf16(af[i], bf_[j], acc[i][j], 0, 0, 0);
    }
    __syncthreads();
  }

#pragma unroll
  for (int i = 0; i < 4; i++)
#pragma unroll
    for (int j = 0; j < 4; j++)
#pragma unroll
      for (int r = 0; r < 4; r++) {
        int row = m0 + wm * 64 + i * 16 + quad * 4 + r;
        int col = n0 + wn * 64 + j * 16 + lo;
        part[(size_t)z * PSTRIDE + (size_t)row * NGATE + col] = acc[i][j][r];
      }
}

// ---------------- hsmean: block-mean of hs fp32 -> [NBLK][HIDN] ----------------
__global__ __launch_bounds__(256) void hsmean_k(const float* __restrict__ hs, float* __restrict__ hsm) {
  int idx = blockIdx.x * 256 + threadIdx.x;   // 65536
  int n = idx >> 11, c = idx & 2047;
  const float* p = hs + (size_t)(n * BLKSZ) * HIDN + c;
  float s = 0.f;
#pragma unroll 8
  for (int r = 0; r < BLKSZ; r++) s += p[(size_t)r * HIDN];
  hsm[idx] = s * (1.0f / 64.0f);
}

// ---------------- kg partial: hsm @ Wk fp32, split-K ----------------
__global__ __launch_bounds__(256) void kg_partial(const float* __restrict__ hsm,
                                                  const float* __restrict__ Wk,
                                                  float* __restrict__ part) {
  __shared__ float hl[32][256];
  int c = blockIdx.x * 256 + threadIdx.x;
  int k0 = blockIdx.y * 256;
#pragma unroll 4
  for (int i = 0; i < 32; i++) hl[i][threadIdx.x] = hsm[(size_t)i * HIDN + k0 + threadIdx.x];
  __syncthreads();
  float acc[32];
#pragma unroll
  for (int n = 0; n < 32; n++) acc[n] = 0.f;
  for (int k4 = 0; k4 < 64; k4++) {
    float w0 = Wk[(size_t)(k0 + k4 * 4 + 0) * HIDN + c];
    float w1 = Wk[(size_t)(k0 + k4 * 4 + 1) * HIDN + c];
    float w2 = Wk[(size_t)(k0 + k4 * 4 + 2) * HIDN + c];
    float w3 = Wk[(size_t)(k0 + k4 * 4 + 3) * HIDN + c];
#pragma unroll
    for (int n = 0; n < 32; n++) {
      float4 hv = *(const float4*)&hl[n][k4 * 4];
      acc[n] += hv.x * w0 + hv.y * w1 + hv.z * w2 + hv.w * w3;
    }
  }
#pragma unroll
  for (int n = 0; n < 32; n++)
    part[((size_t)blockIdx.y * 32 + n) * HIDN + c] = acc[n];
}

__global__ __launch_bounds__(256) void kg_reduce8(const float* __restrict__ part, float* __restrict__ kg) {
  int idx = blockIdx.x * 256 + threadIdx.x;   // 65536
  float s = 0.f;
#pragma unroll
  for (int kc = 0; kc < 8; kc++) s += part[(size_t)kc * 65536 + idx];
  kg[idx] = s;
}

// ---------------- wg[(h*32+n)][r] = sum_d Wq[r][h*128+d] * kg[n][h*128+d] (fp32) ----------------
__global__ __launch_bounds__(256) void wg_k(const float* __restrict__ Wq, const float* __restrict__ kg,
                                            float* __restrict__ wg) {
  __shared__ float kl[32][128];
  int h = blockIdx.y;
  int r = blockIdx.x * 256 + threadIdx.x;
  for (int i = threadIdx.x; i < 32 * 128; i += 256)
    kl[i >> 7][i & 127] = kg[(size_t)(i >> 7) * HIDN + h * HDIM + (i & 127)];
  __syncthreads();
  float acc[32];
#pragma unroll
  for (int n = 0; n < 32; n++) acc[n] = 0.f;
  const float4* wrow = (const float4*)(Wq + (size_t)r * HIDN + h * HDIM);
  for (int d4 = 0; d4 < 32; d4++) {
    float4 w = wrow[d4];
#pragma unroll
    for (int n = 0; n < 32; n++) {
      float4 kv = *(const float4*)&kl[n][d4 * 4];
      acc[n] += w.x * kv.x + w.y * kv.y + w.z * kv.z + w.w * kv.w;
    }
  }
#pragma unroll
  for (int n = 0; n < 32; n++)
    wg[(size_t)(h * 32 + n) * HIDN + r] = acc[n];
}

// ---------------- gate + top-8 -> 32-bit block mask per (h,s) ----------------
__global__ __launch_bounds__(256) void gate_topk(const float* __restrict__ part,
                                                 unsigned* __restrict__ bsel) {
  int w = threadIdx.x >> 6, L = threadIdx.x & 63;
  int p = blockIdx.x * 4 + w;               // p = h*2048 + s
  int h = p >> 11, s = p & 2047;
  int qb = s >> 6;
  int n = L;
  float g = -1e30f;
  if (n == qb) g = 1e30f;
  else if (n < qb) {
    size_t off = (size_t)s * NGATE + h * 32 + n;
    g = part[off] + part[off + PSTRIDE] + part[off + 2 * PSTRIDE] +
        part[off + 3 * PSTRIDE] + part[off + 4 * PSTRIDE] + part[off + 5 * PSTRIDE];
  }
  int rank = 0;
#pragma unroll
  for (int j = 0; j < 32; j++) {
    float gj = __shfl(g, j, 64);
    if (gj > g || (gj == g && j < n)) rank++;
  }
  bool sel = (n <= qb) && (n < 32) && (rank < 8);
  unsigned long long bm = __ballot(sel);
  if (L == 0) bsel[p] = (unsigned)(bm & 0xffffffffull);
}

// ---------------- V^T per head: vt[h][d][s] ----------------
__global__ __launch_bounds__(256) void vtrans(const bh* __restrict__ qkv, bh* __restrict__ vt) {
  __shared__ float tile[32][33];
  int tx = threadIdx.x, ty = threadIdx.y;
  int s0 = blockIdx.x * 32, d0 = blockIdx.y * 32, h = blockIdx.z;
#pragma unroll
  for (int i = 0; i < 4; i++)
    tile[ty + i * 8][tx] = (float)qkv[(size_t)(s0 + ty + i * 8) * NQKV + 2 * HIDN + h * HDIM + d0 + tx];
  __syncthreads();
#pragma unroll
  for (int i = 0; i < 4; i++)
    vt[((size_t)h * HDIM + d0 + ty + i * 8) * SEQ + s0 + tx] = (bh)tile[tx][ty + i * 8];
}

// ---------------- attn v4: 1 WAVE per (h, 16-row q-chunk), no staging, no barriers ----------------
// K/V read directly from global (L2-resident: XCD remap gives each XCD 2 heads ~2MB).
// 2048 independent waves; per-wave 16-row mask union; bf16 P slab per wave in LDS;
// lacc row-sum via ones-MFMA; defer-max (THR=8); setprio around MFMA clusters.
__global__ __launch_bounds__(64) void attn(const bh* __restrict__ qkv, const bh* __restrict__ vt,
                                           const unsigned* __restrict__ bsel, bh* __restrict__ obuf) {
  __shared__ __align__(16) bh PL[16 * 72];        // 2.25 KB per-wave P slab
  const int t = threadIdx.x;                       // 0..63
  const int quad = t >> 4, lo = t & 15;
  // XCD remap: bid&7 = XCD -> 2 heads per XCD (K+V ~2MB fits 4MB L2).
  // qw descending (heavy first); stride-32 CU striping samples qw uniformly.
  const int bid = blockIdx.x;
  const int j = bid >> 3;                          // 0..255 within XCD
  const int h = ((bid & 7) << 1) | (j & 1);
  const int qw = 127 - (j >> 1);                   // 16-row chunk index, 0..127
  const int s0 = qw * 16;
  const int qb = s0 >> 6;                          // q's own 64-block

  unsigned bs[4];
#pragma unroll
  for (int r = 0; r < 4; r++) bs[r] = bsel[h * SEQ + s0 + quad * 4 + r];
  unsigned uni = bs[0] | bs[1] | bs[2] | bs[3];
  uni |= (unsigned)__shfl_xor((int)uni, 16);
  uni |= (unsigned)__shfl_xor((int)uni, 32);       // union over the wave's 16 rows

  bhx8 aq[4];
  const bh* qrow = qkv + (size_t)(s0 + lo) * NQKV + h * HDIM;
#pragma unroll
  for (int ks = 0; ks < 4; ks++) aq[ks] = *(const bhx8*)(qrow + ks * 32 + quad * 8);

  f32x4 oacc[8];
#pragma unroll
  for (int jj = 0; jj < 8; jj++) oacc[jj] = (f32x4){0.f, 0.f, 0.f, 0.f};
  f32x4 lacc = (f32x4){0.f, 0.f, 0.f, 0.f};        // row-sum accumulator (== li)
  float mi[4] = {-1e30f, -1e30f, -1e30f, -1e30f};

  bhx8 ones8;
#pragma unroll
  for (int e = 0; e < 8; e++) ones8[e] = (bh)1.0f;

  const float scale = 0.08838834764831845f;        // 1/sqrt(128)
  const bh* kh = qkv + HIDN + h * HDIM;            // K base for this head
  const bh* vh = vt + (size_t)h * HDIM * SEQ;      // V^T base for this head

  unsigned rem = uni;                              // non-empty: self block always set
  while (rem) {
    const int n = (int)__builtin_ctz(rem);
    rem &= rem - 1;
    const bool self = (n == qb);
    const bh* kbase = kh + (size_t)(n * BLKSZ) * NQKV;

    f32x4 sc[4];
    __builtin_amdgcn_s_setprio(1);
#pragma unroll
    for (int nt = 0; nt < 4; nt++) {
      f32x4 s4 = (f32x4){0.f, 0.f, 0.f, 0.f};
#pragma unroll
      for (int ks = 0; ks < 4; ks++) {
        bhx8 bk = *(const bhx8*)(kbase + (size_t)(nt * 16 + lo) * NQKV + ks * 32 + quad * 8);
        s4 = __builtin_amdgcn_mfma_f32_16x16x32_bf16(aq[ks], bk, s4, 0, 0, 0);
      }
      sc[nt] = s4;
    }
    __builtin_amdgcn_s_setprio(0);

#pragma unroll
    for (int nt = 0; nt < 4; nt++)
#pragma unroll
      for (int r = 0; r < 4; r++) {
        float v = sc[nt][r] * scale;
        int kpos = n * BLKSZ + nt * 16 + lo;
        int qpos = s0 + quad * 4 + r;
        bool ok = ((bs[r] >> n) & 1) && (!self || kpos <= qpos);
        sc[nt][r] = ok ? v : -1e30f;
      }
    float rm[4];
#pragma unroll
    for (int r = 0; r < 4; r++)
      rm[r] = fmaxf(fmaxf(sc[0][r], sc[1][r]), fmaxf(sc[2][r], sc[3][r]));
#pragma unroll
    for (int off = 1; off < 16; off <<= 1)
#pragma unroll
      for (int r = 0; r < 4; r++) rm[r] = fmaxf(rm[r], __shfl_xor(rm[r], off));

    // defer-max (T13, THR=8): rescale only when the running max grew enough.
    bool exceed = (rm[0] > mi[0] + 8.f) || (rm[1] > mi[1] + 8.f) ||
                  (rm[2] > mi[2] + 8.f) || (rm[3] > mi[3] + 8.f);
    if (__any(exceed)) {
      float alpha[4];
#pragma unroll
      for (int r = 0; r < 4; r++) {
        float nm = fmaxf(mi[r], rm[r]);
        alpha[r] = __expf(mi[r] - nm);
        mi[r] = nm;
      }
#pragma unroll
      for (int jj = 0; jj < 8; jj++)
#pragma unroll
        for (int r = 0; r < 4; r++) oacc[jj][r] *= alpha[r];
#pragma unroll
      for (int r = 0; r < 4; r++) lacc[r] *= alpha[r];
    }

#pragma unroll
    for (int nt = 0; nt < 4; nt++)
#pragma unroll
      for (int r = 0; r < 4; r++) {
        float sv = sc[nt][r];
        float pv = (sv > -1e29f) ? __expf(sv - mi[r]) : 0.f;
        PL[(quad * 4 + r) * 72 + nt * 16 + lo] = (bh)pv;
      }

    const bh* vbase = vh + n * BLKSZ;
    __builtin_amdgcn_s_setprio(1);
#pragma unroll
    for (int kk = 0; kk < 2; kk++) {
      bhx8 pa = *(const bhx8*)&PL[lo * 72 + kk * 32 + quad * 8];
      // all-ones B: every output column = row-sum of P -> lacc tracks li for free
      lacc = __builtin_amdgcn_mfma_f32_16x16x32_bf16(pa, ones8, lacc, 0, 0, 0);
#pragma unroll
      for (int jj = 0; jj < 8; jj++) {
        bhx8 vv = *(const bhx8*)(vbase + (size_t)(jj * 16 + lo) * SEQ + kk * 32 + quad * 8);
        oacc[jj] = __builtin_amdgcn_mfma_f32_16x16x32_bf16(pa, vv, oacc[jj], 0, 0, 0);
      }
    }
    __builtin_amdgcn_s_setprio(0);
  }

#pragma unroll
  for (int jj = 0; jj < 8; jj++)
#pragma unroll
    for (int r = 0; r < 4; r++) {
      int row = s0 + quad * 4 + r;
      int col = h * HDIM + jj * 16 + lo;
      obuf[(size_t)row * HIDN + col] = (bh)(oacc[jj][r] / lacc[r]);
    }
}

// ---------------- launch ----------------
extern "C" void kernel_launch(void* const* d_in, const int* in_sizes, int n_in,
                              void* d_out, int out_size, void* d_ws, size_t ws_size,
                              hipStream_t stream) {
  const float* hs = (const float*)d_in[0];
  const float* Wq = (const float*)d_in[1];
  const float* Wk = (const float*)d_in[2];
  const float* Wv = (const float*)d_in[3];
  const float* Wo = (const float*)d_in[4];

  char* ws = (char*)d_ws;
  bh* hs_hi = (bh*)ws;            ws += (size_t)SEQ * HIDN * 2;         // 8 MB
  bh* hs_lo = (bh*)ws;            ws += (size_t)SEQ * HIDN * 2;         // 8 MB
  bh* wqkvT = (bh*)ws;            ws += (size_t)NQKV * HIDN * 2;        // 24 MB
  bh* woT = (bh*)ws;              ws += (size_t)HIDN * HIDN * 2;        // 8 MB
  bh* qkv = (bh*)ws;              ws += (size_t)SEQ * NQKV * 2;         // 24 MB
  bh* vt = (bh*)ws;               ws += (size_t)NHEAD * HDIM * SEQ * 2; // 8 MB
  bh* obuf = (bh*)ws;             ws += (size_t)SEQ * HIDN * 2;         // 8 MB
  float* hsm = (float*)ws;        ws += (size_t)NBLK * HIDN * 4;        // 256 KB
  float* kg_part = (float*)ws;    ws += (size_t)8 * NBLK * HIDN * 4;    // 2 MB
  float* kg = (float*)ws;         ws += (size_t)NBLK * HIDN * 4;        // 256 KB
  float* wg = (float*)ws;         ws += (size_t)NGATE * HIDN * 4;       // 4 MB
  bh* wg_hi = (bh*)ws;            ws += (size_t)NGATE * HIDN * 2;       // 2 MB
  bh* wg_lo = (bh*)ws;            ws += (size_t)NGATE * HIDN * 2;       // 2 MB
  unsigned* bsel = (unsigned*)ws; ws += (size_t)NHEAD * SEQ * 4;        // 128 KB
  // gate partials (6 x 4 MB = 24 MB) alias wqkvT (24 MB): wqkvT is dead after
  // the qkv GEMM, and the stream serializes gemm_bt -> gemm_gate_split.
  float* gpart = (float*)wqkvT;

  // hs split + weight transposes
  split_f32<<<(SEQ * HIDN) / 1024, 256, 0, stream>>>(hs, hs_hi, hs_lo, SEQ * HIDN);
  transpose_cast<<<dim3(64, 64), dim3(32, 8), 0, stream>>>(Wq, wqkvT, HIDN, HIDN);
  transpose_cast<<<dim3(64, 64), dim3(32, 8), 0, stream>>>(Wk, wqkvT + (size_t)HIDN * HIDN, HIDN, HIDN);
  transpose_cast<<<dim3(64, 64), dim3(32, 8), 0, stream>>>(Wv, wqkvT + (size_t)2 * HIDN * HIDN, HIDN, HIDN);
  transpose_cast<<<dim3(64, 64), dim3(32, 8), 0, stream>>>(Wo, woT, HIDN, HIDN);

  // qkv bf16
  gemm_bt<<<dim3(NQKV / 128, SEQ / 128), 256, 0, stream>>>(hs_hi, wqkvT, qkv, SEQ, NQKV, HIDN);

  // fp32 gate path (wqkvT dead from here; gpart aliases it)
  hsmean_k<<<(NBLK * HIDN) / 256, 256, 0, stream>>>(hs, hsm);
  kg_partial<<<dim3(8, 8), 256, 0, stream>>>(hsm, Wk, kg_part);
  kg_reduce8<<<(NBLK * HIDN) / 256, 256, 0, stream>>>(kg_part, kg);
  wg_k<<<dim3(8, NHEAD), 256, 0, stream>>>(Wq, kg, wg);
  split_f32<<<(NGATE * HIDN) / 1024, 256, 0, stream>>>(wg, wg_hi, wg_lo, NGATE * HIDN);
  gemm_gate_split<<<dim3(NGATE / 128, SEQ / 128, 6), 256, 0, stream>>>(hs_hi, hs_lo, wg_hi, wg_lo, gpart);
  gate_topk<<<(NHEAD * SEQ) / 4, 256, 0, stream>>>(gpart, bsel);

  // attention (1 wave per 16 q-rows; XCD-aware remap inside the kernel)
  vtrans<<<dim3(SEQ / 32, HDIM / 32, NHEAD), dim3(32, 8), 0, stream>>>(qkv, vt);
  attn<<<dim3(NHEAD * SEQ / 16), 64, 0, stream>>>(qkv, vt, bsel, obuf);

  // output projection (128x128 tiles -> 256 blocks = full CU fill)
  gemm_bt128f<<<dim3(HIDN / 128, SEQ / 128), 256, 0, stream>>>(obuf, woT, (float*)d_out, SEQ, HIDN, HIDN);
}

// Round 4
// 488.967 us; speedup vs baseline: 1.2357x; 1.2357x over previous
//
#include <hip/hip_runtime.h>
#include <hip/hip_bf16.h>
#include <stdint.h>
#include <stddef.h>

// MoBA forward, MI355X.
//  split hs -> bf16 hi/lo; transpose-cast W's -> B^T bf16
//  GEMM1 (bf16 MFMA, LDS-staged coalesced bf16 epilogue): qkv[2048][6144]
//  fp32 gate path: hsmean -> kg (fp32) -> wg = Wq_h @ kg_h (fp32)
//    gate partials = bf16x3 MFMA split 6 ways (3 phases x 2 K-halves), 128^2 tiles
//  gate_topk: sums 6 partials, rank-based top-8 -> 32-bit block mask
//  attn v5: v3 structure (dbuf K/V via global_load_lds + XOR swizzle, counted
//    vmcnt(8) + raw s_barrier, bf16 P, lacc ones-MFMA, defer-max, balanced
//    qb pairing) + per-WAVE block skip (16-row union) + fma-folded mask.
//  GEMM2: o @ Wo on 128^2 tiles -> d_out fp32

using bh = __bf16;
typedef __bf16 bhx8 __attribute__((ext_vector_type(8)));
typedef __bf16 bhx4 __attribute__((ext_vector_type(4)));
typedef float  f32x4 __attribute__((ext_vector_type(4)));

#define SEQ   2048
#define HIDN  2048
#define NHEAD 16
#define HDIM  128
#define NBLK  32
#define BLKSZ 64
#define NQKV  6144
#define NGATE 512   // NBLK*NHEAD gate columns
#define LDK   72    // padded LDS row stride for GEMM K-tiles (64+8)
#define LDC   136   // C-tile epilogue stride: 272 B/row = 16B-aligned, 2-way banks (free)
#define PSTRIDE ((size_t)SEQ * NGATE)   // gate partial plane stride

// global -> LDS direct copy, 16 B per lane; LDS dest = wave-uniform base + lane*16
#define GLDS16(gsrc, ldst)                                                     \
  __builtin_amdgcn_global_load_lds(                                            \
      (const __attribute__((address_space(1))) uint32_t*)(gsrc),               \
      (__attribute__((address_space(3))) uint32_t*)(ldst), 16, 0, 0)

// ---------------- split fp32 -> bf16 hi + lo ----------------
__global__ __launch_bounds__(256) void split_f32(const float* __restrict__ in,
                                                 bh* __restrict__ hi, bh* __restrict__ lo, int n) {
  int i = (blockIdx.x * 256 + threadIdx.x) * 4;
  if (i >= n) return;
  float4 v = *(const float4*)(in + i);
  bhx4 h4, l4;
  float vv[4] = {v.x, v.y, v.z, v.w};
#pragma unroll
  for (int e = 0; e < 4; e++) {
    bh h = (bh)vv[e];
    h4[e] = h;
    l4[e] = (bh)(vv[e] - (float)h);
  }
  *(bhx4*)(hi + i) = h4;
  *(bhx4*)(lo + i) = l4;
}

// ---------------- transpose + cast: in[R][C] fp32 -> out[C][R] bf16 ----------------
__global__ __launch_bounds__(256) void transpose_cast(const float* __restrict__ in,
                                                      bh* __restrict__ out, int R, int C) {
  __shared__ float tile[32][33];
  int tx = threadIdx.x, ty = threadIdx.y;
  int c0 = blockIdx.x * 32, r0 = blockIdx.y * 32;
#pragma unroll
  for (int i = 0; i < 4; i++)
    tile[ty + i * 8][tx] = in[(size_t)(r0 + ty + i * 8) * C + c0 + tx];
  __syncthreads();
#pragma unroll
  for (int i = 0; i < 4; i++)
    out[(size_t)(c0 + ty + i * 8) * R + r0 + tx] = (bh)tile[tx][ty + i * 8];
}

// ---------------- bf16 MFMA GEMM 128x128, B^T layout, coalesced bf16 epilogue ----------------
// C[M][N] = A[M][K] * BT[N][K]^T ; bf16 out via LDS restage + uint4 stores.
__global__ __launch_bounds__(256) void gemm_bt(const bh* __restrict__ A, const bh* __restrict__ BT,
                                               bh* __restrict__ Cb, int M, int N, int K) {
  __shared__ __align__(16) bh smem[2 * 128 * LDK];   // 36 KB; reused as 128xLDC C-tile (34 KB)
  bh* As = smem;
  bh* Bs = smem + 128 * LDK;
  const int t = threadIdx.x;
  const int L = t & 63, w = t >> 6;
  const int wm = w & 1, wn = w >> 1;
  const int quad = L >> 4, lo = L & 15;
  const int m0 = blockIdx.y * 128, n0 = blockIdx.x * 128;

  f32x4 acc[4][4];
#pragma unroll
  for (int i = 0; i < 4; i++)
#pragma unroll
    for (int j = 0; j < 4; j++) acc[i][j] = (f32x4){0.f, 0.f, 0.f, 0.f};

  for (int k0 = 0; k0 < K; k0 += 64) {
#pragma unroll
    for (int c = 0; c < 4; c++) {
      int i = c * 256 + t;
      int row = i >> 3, cg = i & 7;
      *(uint4*)&As[row * LDK + cg * 8] = *(const uint4*)(A + (size_t)(m0 + row) * K + k0 + cg * 8);
      *(uint4*)&Bs[row * LDK + cg * 8] = *(const uint4*)(BT + (size_t)(n0 + row) * K + k0 + cg * 8);
    }
    __syncthreads();
#pragma unroll
    for (int ks = 0; ks < 2; ks++) {
      bhx8 af[4], bf_[4];
#pragma unroll
      for (int i = 0; i < 4; i++)
        af[i] = *(const bhx8*)&As[(wm * 64 + i * 16 + lo) * LDK + ks * 32 + quad * 8];
#pragma unroll
      for (int j = 0; j < 4; j++)
        bf_[j] = *(const bhx8*)&Bs[(wn * 64 + j * 16 + lo) * LDK + ks * 32 + quad * 8];
#pragma unroll
      for (int i = 0; i < 4; i++)
#pragma unroll
        for (int j = 0; j < 4; j++)
          acc[i][j] = __builtin_amdgcn_mfma_f32_16x16x32_bf16(af[i], bf_[j], acc[i][j], 0, 0, 0);
    }
    __syncthreads();
  }

  // epilogue: scatter acc -> LDS C-tile, then fully-coalesced 16B global stores
  bh* Cs = smem;
#pragma unroll
  for (int i = 0; i < 4; i++)
#pragma unroll
    for (int j = 0; j < 4; j++)
#pragma unroll
      for (int r = 0; r < 4; r++)
        Cs[(wm * 64 + i * 16 + quad * 4 + r) * LDC + wn * 64 + j * 16 + lo] = (bh)acc[i][j][r];
  __syncthreads();
#pragma unroll
  for (int it = 0; it < 8; it++) {
    int idx = it * 256 + t;                 // 2048 chunks: 128 rows x 16
    int row = idx >> 4, cg = idx & 15;
    *(uint4*)(Cb + (size_t)(m0 + row) * N + n0 + cg * 8) = *(const uint4*)&Cs[row * LDC + cg * 8];
  }
}

// ---------------- bf16 MFMA GEMM 128x128, B^T layout, fp32 out (o-projection) ----------------
__global__ __launch_bounds__(256) void gemm_bt128f(const bh* __restrict__ A, const bh* __restrict__ BT,
                                                   float* __restrict__ Cf, int M, int N, int K) {
  __shared__ __align__(16) bh smem[2 * 128 * LDK];
  bh* As = smem;
  bh* Bs = smem + 128 * LDK;
  const int t = threadIdx.x;
  const int L = t & 63, w = t >> 6;
  const int wm = w & 1, wn = w >> 1;
  const int quad = L >> 4, lo = L & 15;
  const int m0 = blockIdx.y * 128, n0 = blockIdx.x * 128;

  f32x4 acc[4][4];
#pragma unroll
  for (int i = 0; i < 4; i++)
#pragma unroll
    for (int j = 0; j < 4; j++) acc[i][j] = (f32x4){0.f, 0.f, 0.f, 0.f};

  for (int k0 = 0; k0 < K; k0 += 64) {
#pragma unroll
    for (int c = 0; c < 4; c++) {
      int i = c * 256 + t;
      int row = i >> 3, cg = i & 7;
      *(uint4*)&As[row * LDK + cg * 8] = *(const uint4*)(A + (size_t)(m0 + row) * K + k0 + cg * 8);
      *(uint4*)&Bs[row * LDK + cg * 8] = *(const uint4*)(BT + (size_t)(n0 + row) * K + k0 + cg * 8);
    }
    __syncthreads();
#pragma unroll
    for (int ks = 0; ks < 2; ks++) {
      bhx8 af[4], bf_[4];
#pragma unroll
      for (int i = 0; i < 4; i++)
        af[i] = *(const bhx8*)&As[(wm * 64 + i * 16 + lo) * LDK + ks * 32 + quad * 8];
#pragma unroll
      for (int j = 0; j < 4; j++)
        bf_[j] = *(const bhx8*)&Bs[(wn * 64 + j * 16 + lo) * LDK + ks * 32 + quad * 8];
#pragma unroll
      for (int i = 0; i < 4; i++)
#pragma unroll
        for (int j = 0; j < 4; j++)
          acc[i][j] = __builtin_amdgcn_mfma_f32_16x16x32_bf16(af[i], bf_[j], acc[i][j], 0, 0, 0);
    }
    __syncthreads();
  }

  // fp32 stores: 16 lanes x 4 B = full 64 B sectors per quad-row (no amplification)
#pragma unroll
  for (int i = 0; i < 4; i++)
#pragma unroll
    for (int j = 0; j < 4; j++)
#pragma unroll
      for (int r = 0; r < 4; r++) {
        int row = m0 + wm * 64 + i * 16 + quad * 4 + r;
        int col = n0 + wn * 64 + j * 16 + lo;
        Cf[(size_t)row * N + col] = acc[i][j][r];
      }
}

// ---------------- gate GEMM, 6-way split, 128^2 tiles ----------------
// z = phase*2 + khalf; phase 0: hi@wgh, 1: lo@wgh, 2: hi@wgl; K=1024 each.
__global__ __launch_bounds__(256) void gemm_gate_split(const bh* __restrict__ hs_hi,
                                                       const bh* __restrict__ hs_lo,
                                                       const bh* __restrict__ wg_hi,
                                                       const bh* __restrict__ wg_lo,
                                                       float* __restrict__ part) {
  __shared__ __align__(16) bh smem[2 * 128 * LDK];
  bh* As = smem;
  bh* Bs = smem + 128 * LDK;
  const int t = threadIdx.x;
  const int L = t & 63, w = t >> 6;
  const int wm = w & 1, wn = w >> 1;
  const int quad = L >> 4, lo = L & 15;
  const int m0 = blockIdx.y * 128, n0 = blockIdx.x * 128;
  const int z = blockIdx.z;
  const bh* Ap = ((z >> 1) == 1) ? hs_lo : hs_hi;
  const bh* Bp = ((z >> 1) == 2) ? wg_lo : wg_hi;
  const int kb = (z & 1) * 1024;

  f32x4 acc[4][4];
#pragma unroll
  for (int i = 0; i < 4; i++)
#pragma unroll
    for (int j = 0; j < 4; j++) acc[i][j] = (f32x4){0.f, 0.f, 0.f, 0.f};

  for (int k0 = 0; k0 < 1024; k0 += 64) {
#pragma unroll
    for (int c = 0; c < 4; c++) {
      int i = c * 256 + t;
      int row = i >> 3, cg = i & 7;
      *(uint4*)&As[row * LDK + cg * 8] = *(const uint4*)(Ap + (size_t)(m0 + row) * HIDN + kb + k0 + cg * 8);
      *(uint4*)&Bs[row * LDK + cg * 8] = *(const uint4*)(Bp + (size_t)(n0 + row) * HIDN + kb + k0 + cg * 8);
    }
    __syncthreads();
#pragma unroll
    for (int ks = 0; ks < 2; ks++) {
      bhx8 af[4], bf_[4];
#pragma unroll
      for (int i = 0; i < 4; i++)
        af[i] = *(const bhx8*)&As[(wm * 64 + i * 16 + lo) * LDK + ks * 32 + quad * 8];
#pragma unroll
      for (int j = 0; j < 4; j++)
        bf_[j] = *(const bhx8*)&Bs[(wn * 64 + j * 16 + lo) * LDK + ks * 32 + quad * 8];
#pragma unroll
      for (int i = 0; i < 4; i++)
#pragma unroll
        for (int j = 0; j < 4; j++)
          acc[i][j] = __builtin_amdgcn_mfma_f32_16x16x32_bf16(af[i], bf_[j], acc[i][j], 0, 0, 0);
    }
    __syncthreads();
  }

#pragma unroll
  for (int i = 0; i < 4; i++)
#pragma unroll
    for (int j = 0; j < 4; j++)
#pragma unroll
      for (int r = 0; r < 4; r++) {
        int row = m0 + wm * 64 + i * 16 + quad * 4 + r;
        int col = n0 + wn * 64 + j * 16 + lo;
        part[(size_t)z * PSTRIDE + (size_t)row * NGATE + col] = acc[i][j][r];
      }
}

// ---------------- hsmean: block-mean of hs fp32 -> [NBLK][HIDN] ----------------
__global__ __launch_bounds__(256) void hsmean_k(const float* __restrict__ hs, float* __restrict__ hsm) {
  int idx = blockIdx.x * 256 + threadIdx.x;   // 65536
  int n = idx >> 11, c = idx & 2047;
  const float* p = hs + (size_t)(n * BLKSZ) * HIDN + c;
  float s = 0.f;
#pragma unroll 8
  for (int r = 0; r < BLKSZ; r++) s += p[(size_t)r * HIDN];
  hsm[idx] = s * (1.0f / 64.0f);
}

// ---------------- kg partial: hsm @ Wk fp32, split-K ----------------
__global__ __launch_bounds__(256) void kg_partial(const float* __restrict__ hsm,
                                                  const float* __restrict__ Wk,
                                                  float* __restrict__ part) {
  __shared__ float hl[32][256];
  int c = blockIdx.x * 256 + threadIdx.x;
  int k0 = blockIdx.y * 256;
#pragma unroll 4
  for (int i = 0; i < 32; i++) hl[i][threadIdx.x] = hsm[(size_t)i * HIDN + k0 + threadIdx.x];
  __syncthreads();
  float acc[32];
#pragma unroll
  for (int n = 0; n < 32; n++) acc[n] = 0.f;
  for (int k4 = 0; k4 < 64; k4++) {
    float w0 = Wk[(size_t)(k0 + k4 * 4 + 0) * HIDN + c];
    float w1 = Wk[(size_t)(k0 + k4 * 4 + 1) * HIDN + c];
    float w2 = Wk[(size_t)(k0 + k4 * 4 + 2) * HIDN + c];
    float w3 = Wk[(size_t)(k0 + k4 * 4 + 3) * HIDN + c];
#pragma unroll
    for (int n = 0; n < 32; n++) {
      float4 hv = *(const float4*)&hl[n][k4 * 4];
      acc[n] += hv.x * w0 + hv.y * w1 + hv.z * w2 + hv.w * w3;
    }
  }
#pragma unroll
  for (int n = 0; n < 32; n++)
    part[((size_t)blockIdx.y * 32 + n) * HIDN + c] = acc[n];
}

__global__ __launch_bounds__(256) void kg_reduce8(const float* __restrict__ part, float* __restrict__ kg) {
  int idx = blockIdx.x * 256 + threadIdx.x;   // 65536
  float s = 0.f;
#pragma unroll
  for (int kc = 0; kc < 8; kc++) s += part[(size_t)kc * 65536 + idx];
  kg[idx] = s;
}

// ---------------- wg[(h*32+n)][r] = sum_d Wq[r][h*128+d] * kg[n][h*128+d] (fp32) ----------------
__global__ __launch_bounds__(256) void wg_k(const float* __restrict__ Wq, const float* __restrict__ kg,
                                            float* __restrict__ wg) {
  __shared__ float kl[32][128];
  int h = blockIdx.y;
  int r = blockIdx.x * 256 + threadIdx.x;
  for (int i = threadIdx.x; i < 32 * 128; i += 256)
    kl[i >> 7][i & 127] = kg[(size_t)(i >> 7) * HIDN + h * HDIM + (i & 127)];
  __syncthreads();
  float acc[32];
#pragma unroll
  for (int n = 0; n < 32; n++) acc[n] = 0.f;
  const float4* wrow = (const float4*)(Wq + (size_t)r * HIDN + h * HDIM);
  for (int d4 = 0; d4 < 32; d4++) {
    float4 w = wrow[d4];
#pragma unroll
    for (int n = 0; n < 32; n++) {
      float4 kv = *(const float4*)&kl[n][d4 * 4];
      acc[n] += w.x * kv.x + w.y * kv.y + w.z * kv.z + w.w * kv.w;
    }
  }
#pragma unroll
  for (int n = 0; n < 32; n++)
    wg[(size_t)(h * 32 + n) * HIDN + r] = acc[n];
}

// ---------------- gate + top-8 -> 32-bit block mask per (h,s) ----------------
__global__ __launch_bounds__(256) void gate_topk(const float* __restrict__ part,
                                                 unsigned* __restrict__ bsel) {
  int w = threadIdx.x >> 6, L = threadIdx.x & 63;
  int p = blockIdx.x * 4 + w;               // p = h*2048 + s
  int h = p >> 11, s = p & 2047;
  int qb = s >> 6;
  int n = L;
  float g = -1e30f;
  if (n == qb) g = 1e30f;
  else if (n < qb) {
    size_t off = (size_t)s * NGATE + h * 32 + n;
    g = part[off] + part[off + PSTRIDE] + part[off + 2 * PSTRIDE] +
        part[off + 3 * PSTRIDE] + part[off + 4 * PSTRIDE] + part[off + 5 * PSTRIDE];
  }
  int rank = 0;
#pragma unroll
  for (int j = 0; j < 32; j++) {
    float gj = __shfl(g, j, 64);
    if (gj > g || (gj == g && j < n)) rank++;
  }
  bool sel = (n <= qb) && (n < 32) && (rank < 8);
  unsigned long long bm = __ballot(sel);
  if (L == 0) bsel[p] = (unsigned)(bm & 0xffffffffull);
}

// ---------------- V^T per head: vt[h][d][s] ----------------
__global__ __launch_bounds__(256) void vtrans(const bh* __restrict__ qkv, bh* __restrict__ vt) {
  __shared__ float tile[32][33];
  int tx = threadIdx.x, ty = threadIdx.y;
  int s0 = blockIdx.x * 32, d0 = blockIdx.y * 32, h = blockIdx.z;
#pragma unroll
  for (int i = 0; i < 4; i++)
    tile[ty + i * 8][tx] = (float)qkv[(size_t)(s0 + ty + i * 8) * NQKV + 2 * HIDN + h * HDIM + d0 + tx];
  __syncthreads();
#pragma unroll
  for (int i = 0; i < 4; i++)
    vt[((size_t)h * HDIM + d0 + ty + i * 8) * SEQ + s0 + tx] = (bh)tile[tx][ty + i * 8];
}

// ---------------- attn v5: 1 workgroup (4 waves) per (h, 64-row q-block) ----------------
// v3 structure + per-wave block skip (16-row union) + fma-folded non-self mask.
__global__ __launch_bounds__(256) void attn(const bh* __restrict__ qkv, const bh* __restrict__ vt,
                                            const unsigned* __restrict__ bsel, bh* __restrict__ obuf) {
  __shared__ __align__(16) bh Ksm[2][64 * 128];   // 2 x 16 KB, linear 256 B rows, XOR-swizzled
  __shared__ __align__(16) bh Vsm[2][128 * 64];   // 2 x 16 KB, linear 128 B rows, XOR-swizzled
  __shared__ __align__(16) bh PLb[4][16 * 72];    // bf16 P, 144 B rows (16B-aligned, 2-way banks)
  __shared__ unsigned ublk;
  const int t = threadIdx.x;
  const int w = t >> 6, L = t & 63;
  const int quad = L >> 4, lo = L & 15;
  // XCD-aware remap: bid&7 = XCD -> 2 heads per XCD (K/V ~2MB fits 4MB L2).
  // Balanced pairing: jj<32 heavy (qb 31..16, dispatched first), jj>=32 light.
  const int bid = blockIdx.x;
  const int jj = bid >> 3;
  const int h = ((bid & 7) << 1) | (jj & 1);
  const int qb = (jj < 32) ? (31 - (jj >> 1)) : ((jj - 32) >> 1);
  const int s0 = qb * 64 + w * 16;

  unsigned bs[4];
#pragma unroll
  for (int r = 0; r < 4; r++) bs[r] = bsel[h * SEQ + s0 + quad * 4 + r];
  unsigned uni = bs[0] | bs[1] | bs[2] | bs[3];
  uni |= (unsigned)__shfl_xor((int)uni, 16);
  uni |= (unsigned)__shfl_xor((int)uni, 32);
  const unsigned uniw = uni;                 // this wave's 16-row union
  if (t == 0) ublk = 0;
  __syncthreads();
  if (L == 0) atomicOr(&ublk, uni);
  __syncthreads();
  const unsigned un = ublk;                  // WG-level union (drives staging loop)

  bhx8 aq[4];
  const bh* qrow = qkv + (size_t)(s0 + lo) * NQKV + h * HDIM;
#pragma unroll
  for (int ks = 0; ks < 4; ks++) aq[ks] = *(const bhx8*)(qrow + ks * 32 + quad * 8);

  f32x4 oacc[8];
#pragma unroll
  for (int j = 0; j < 8; j++) oacc[j] = (f32x4){0.f, 0.f, 0.f, 0.f};
  f32x4 lacc = (f32x4){0.f, 0.f, 0.f, 0.f};       // row-sum accumulator (== li)
  float mi[4] = {-1e30f, -1e30f, -1e30f, -1e30f};

  bhx8 ones8;
#pragma unroll
  for (int e = 0; e < 8; e++) ones8[e] = (bh)1.0f;

  const float scale = 0.08838834764831845f;  // 1/sqrt(128)

  // stage K tile (64 rows x 256 B) + V tile (128 rows x 128 B) for block n into buffer b.
  // LDS linear; the XOR swizzle (byte ^= (row&7)<<4) is applied to the GLOBAL source
  // address (global_load_lds dest must be contiguous), and again on the ds_read side.
  auto stageKV = [&](int b, int n) {
    const char* ksrc = (const char*)(qkv + (size_t)(n * BLKSZ) * NQKV + HIDN + h * HDIM);
    const char* vsrc = (const char*)(vt + ((size_t)h * HDIM) * SEQ + n * BLKSZ);
    char* kb = (char*)&Ksm[b][0];
    char* vb = (char*)&Vsm[b][0];
#pragma unroll
    for (int it = 0; it < 4; it++) {
      int idx = it * 256 + t;                 // 1024 chunks of 16 B: row = idx>>4
      int row = idx >> 4, x = (idx & 15) << 4;
      GLDS16(ksrc + (size_t)row * (NQKV * 2) + (x ^ ((row & 7) << 4)),
             kb + ((idx >> 6) << 10));        // wave-uniform base; HW adds lane*16
    }
#pragma unroll
    for (int it = 0; it < 4; it++) {
      int idx = it * 256 + t;                 // 1024 chunks of 16 B: row = idx>>3
      int row = idx >> 3, x = (idx & 7) << 4;
      GLDS16(vsrc + (size_t)row * (SEQ * 2) + (x ^ ((row & 7) << 4)),
             vb + ((idx >> 6) << 10));
    }
  };

  unsigned rem = un;                          // un != 0 (self block always set)
  int ncur = (int)__builtin_ctz(rem);
  rem &= rem - 1;
  stageKV(0, ncur);
  int cur = 0;

  while (true) {
    int nnext = -1;
    if (rem) { nnext = (int)__builtin_ctz(rem); rem &= rem - 1; }
    if (nnext >= 0) {
      stageKV(cur ^ 1, nnext);
      // 8 newest outstanding = next-tile loads; wait only for current tile (+Q).
      asm volatile("s_waitcnt vmcnt(8)" ::: "memory");
    } else {
      asm volatile("s_waitcnt vmcnt(0)" ::: "memory");
    }
    __builtin_amdgcn_s_barrier();

    // per-wave skip: none of this wave's 16 rows selected block ncur ->
    // its contribution is all-masked zeros; skip compute, keep barriers.
    if ((uniw >> ncur) & 1) {
      const char* Kc = (const char*)&Ksm[cur][0];
      const char* Vc = (const char*)&Vsm[cur][0];
      const bool self = (ncur == qb);

      f32x4 sc[4];
      __builtin_amdgcn_s_setprio(1);
#pragma unroll
      for (int nt = 0; nt < 4; nt++) {
        f32x4 s4 = (f32x4){0.f, 0.f, 0.f, 0.f};
#pragma unroll
        for (int ks = 0; ks < 4; ks++) {
          const int row = nt * 16 + lo;
          bhx8 bk = *(const bhx8*)(Kc + row * 256 + ((ks * 64 + quad * 16) ^ ((row & 7) << 4)));
          s4 = __builtin_amdgcn_mfma_f32_16x16x32_bf16(aq[ks], bk, s4, 0, 0, 0);
        }
        sc[nt] = s4;
      }
      __builtin_amdgcn_s_setprio(0);

      if (self) {
#pragma unroll
        for (int nt = 0; nt < 4; nt++)
#pragma unroll
          for (int r = 0; r < 4; r++) {
            float v = sc[nt][r] * scale;
            int kpos = ncur * BLKSZ + nt * 16 + lo;
            int qpos = s0 + quad * 4 + r;
            bool ok = ((bs[r] >> ncur) & 1) && (kpos <= qpos);
            sc[nt][r] = ok ? v : -1e30f;
          }
      } else {
        float bias[4];
#pragma unroll
        for (int r = 0; r < 4; r++)
          bias[r] = ((bs[r] >> ncur) & 1) ? 0.f : -1e30f;
#pragma unroll
        for (int nt = 0; nt < 4; nt++)
#pragma unroll
          for (int r = 0; r < 4; r++)
            sc[nt][r] = sc[nt][r] * scale + bias[r];
      }
      float rm[4];
#pragma unroll
      for (int r = 0; r < 4; r++)
        rm[r] = fmaxf(fmaxf(sc[0][r], sc[1][r]), fmaxf(sc[2][r], sc[3][r]));
#pragma unroll
      for (int off = 1; off < 16; off <<= 1)
#pragma unroll
        for (int r = 0; r < 4; r++) rm[r] = fmaxf(rm[r], __shfl_xor(rm[r], off));

      // defer-max (T13, THR=8): rescale only when the running max grew enough.
      bool exceed = (rm[0] > mi[0] + 8.f) || (rm[1] > mi[1] + 8.f) ||
                    (rm[2] > mi[2] + 8.f) || (rm[3] > mi[3] + 8.f);
      if (__any(exceed)) {
        float alpha[4];
#pragma unroll
        for (int r = 0; r < 4; r++) {
          float nm = fmaxf(mi[r], rm[r]);
          alpha[r] = __expf(mi[r] - nm);
          mi[r] = nm;
        }
#pragma unroll
        for (int j = 0; j < 8; j++)
#pragma unroll
          for (int r = 0; r < 4; r++) oacc[j][r] *= alpha[r];
#pragma unroll
        for (int r = 0; r < 4; r++) lacc[r] *= alpha[r];
      }

#pragma unroll
      for (int nt = 0; nt < 4; nt++)
#pragma unroll
        for (int r = 0; r < 4; r++) {
          float sv = sc[nt][r];
          float pv = (sv > -1e29f) ? __expf(sv - mi[r]) : 0.f;
          PLb[w][(quad * 4 + r) * 72 + nt * 16 + lo] = (bh)pv;   // per-wave slab
        }

      __builtin_amdgcn_s_setprio(1);
#pragma unroll
      for (int kk = 0; kk < 2; kk++) {
        bhx8 pa = *(const bhx8*)&PLb[w][lo * 72 + kk * 32 + quad * 8];
        // all-ones B: every output column = row-sum of P -> lacc tracks li for free
        lacc = __builtin_amdgcn_mfma_f32_16x16x32_bf16(pa, ones8, lacc, 0, 0, 0);
#pragma unroll
        for (int j = 0; j < 8; j++) {
          const int row = j * 16 + lo;
          bhx8 vv = *(const bhx8*)(Vc + row * 128 + ((kk * 64 + quad * 16) ^ ((row & 7) << 4)));
          oacc[j] = __builtin_amdgcn_mfma_f32_16x16x32_bf16(pa, vv, oacc[j], 0, 0, 0);
        }
      }
      __builtin_amdgcn_s_setprio(0);
    }

    __builtin_amdgcn_s_barrier();   // all waves done reading buf[cur] before it is restaged
    if (nnext < 0) break;
    ncur = nnext;
    cur ^= 1;
  }

#pragma unroll
  for (int j = 0; j < 8; j++)
#pragma unroll
    for (int r = 0; r < 4; r++) {
      int row = s0 + quad * 4 + r;
      int col = h * HDIM + j * 16 + lo;
      obuf[(size_t)row * HIDN + col] = (bh)(oacc[j][r] / lacc[r]);
    }
}

// ---------------- launch ----------------
extern "C" void kernel_launch(void* const* d_in, const int* in_sizes, int n_in,
                              void* d_out, int out_size, void* d_ws, size_t ws_size,
                              hipStream_t stream) {
  const float* hs = (const float*)d_in[0];
  const float* Wq = (const float*)d_in[1];
  const float* Wk = (const float*)d_in[2];
  const float* Wv = (const float*)d_in[3];
  const float* Wo = (const float*)d_in[4];

  char* ws = (char*)d_ws;
  bh* hs_hi = (bh*)ws;            ws += (size_t)SEQ * HIDN * 2;         // 8 MB
  bh* hs_lo = (bh*)ws;            ws += (size_t)SEQ * HIDN * 2;         // 8 MB
  bh* wqkvT = (bh*)ws;            ws += (size_t)NQKV * HIDN * 2;        // 24 MB
  bh* woT = (bh*)ws;              ws += (size_t)HIDN * HIDN * 2;        // 8 MB
  bh* qkv = (bh*)ws;              ws += (size_t)SEQ * NQKV * 2;         // 24 MB
  bh* vt = (bh*)ws;               ws += (size_t)NHEAD * HDIM * SEQ * 2; // 8 MB
  bh* obuf = (bh*)ws;             ws += (size_t)SEQ * HIDN * 2;         // 8 MB
  float* hsm = (float*)ws;        ws += (size_t)NBLK * HIDN * 4;        // 256 KB
  float* kg_part = (float*)ws;    ws += (size_t)8 * NBLK * HIDN * 4;    // 2 MB
  float* kg = (float*)ws;         ws += (size_t)NBLK * HIDN * 4;        // 256 KB
  float* wg = (float*)ws;         ws += (size_t)NGATE * HIDN * 4;       // 4 MB
  bh* wg_hi = (bh*)ws;            ws += (size_t)NGATE * HIDN * 2;       // 2 MB
  bh* wg_lo = (bh*)ws;            ws += (size_t)NGATE * HIDN * 2;       // 2 MB
  unsigned* bsel = (unsigned*)ws; ws += (size_t)NHEAD * SEQ * 4;        // 128 KB
  // gate partials (6 x 4 MB = 24 MB) alias wqkvT (24 MB): wqkvT is dead after
  // the qkv GEMM, and the stream serializes gemm_bt -> gemm_gate_split.
  float* gpart = (float*)wqkvT;

  // hs split + weight transposes
  split_f32<<<(SEQ * HIDN) / 1024, 256, 0, stream>>>(hs, hs_hi, hs_lo, SEQ * HIDN);
  transpose_cast<<<dim3(64, 64), dim3(32, 8), 0, stream>>>(Wq, wqkvT, HIDN, HIDN);
  transpose_cast<<<dim3(64, 64), dim3(32, 8), 0, stream>>>(Wk, wqkvT + (size_t)HIDN * HIDN, HIDN, HIDN);
  transpose_cast<<<dim3(64, 64), dim3(32, 8), 0, stream>>>(Wv, wqkvT + (size_t)2 * HIDN * HIDN, HIDN, HIDN);
  transpose_cast<<<dim3(64, 64), dim3(32, 8), 0, stream>>>(Wo, woT, HIDN, HIDN);

  // qkv bf16
  gemm_bt<<<dim3(NQKV / 128, SEQ / 128), 256, 0, stream>>>(hs_hi, wqkvT, qkv, SEQ, NQKV, HIDN);

  // fp32 gate path (wqkvT dead from here; gpart aliases it)
  hsmean_k<<<(NBLK * HIDN) / 256, 256, 0, stream>>>(hs, hsm);
  kg_partial<<<dim3(8, 8), 256, 0, stream>>>(hsm, Wk, kg_part);
  kg_reduce8<<<(NBLK * HIDN) / 256, 256, 0, stream>>>(kg_part, kg);
  wg_k<<<dim3(8, NHEAD), 256, 0, stream>>>(Wq, kg, wg);
  split_f32<<<(NGATE * HIDN) / 1024, 256, 0, stream>>>(wg, wg_hi, wg_lo, NGATE * HIDN);
  gemm_gate_split<<<dim3(NGATE / 128, SEQ / 128, 6), 256, 0, stream>>>(hs_hi, hs_lo, wg_hi, wg_lo, gpart);
  gate_topk<<<(NHEAD * SEQ) / 4, 256, 0, stream>>>(gpart, bsel);

  // attention (1D grid, XCD-aware remap inside the kernel)
  vtrans<<<dim3(SEQ / 32, HDIM / 32, NHEAD), dim3(32, 8), 0, stream>>>(qkv, vt);
  attn<<<dim3(NBLK * NHEAD), 256, 0, stream>>>(qkv, vt, bsel, obuf);

  // output projection (128x128 tiles -> 256 blocks = full CU fill)
  gemm_bt128f<<<dim3(HIDN / 128, SEQ / 128), 256, 0, stream>>>(obuf, woT, (float*)d_out, SEQ, HIDN, HIDN);
}

// Round 5
// 469.250 us; speedup vs baseline: 1.2877x; 1.0420x over previous
//
#include <hip/hip_runtime.h>
#include <hip/hip_bf16.h>
#include <stdint.h>
#include <stddef.h>

// MoBA forward, MI355X.
//  split hs -> bf16 hi/lo; transpose-cast W's -> B^T bf16 (fused 4-in-1)
//  GEMM1 (bf16 MFMA, global_load_lds staged, m97-style): qkv[2048][6144]
//  fp32 gate path: hsmean -> kg (fp32) -> wg = Wq_h @ kg_h (fp32)
//    gate partials = bf16x3 MFMA split 6 ways, 128^2 tiles, GLDS-staged
//  gate_topk: sums 6 partials, rank-based top-8 -> 32-bit block mask
//  attn v5: dbuf K/V via global_load_lds + XOR swizzle, counted vmcnt(8) +
//    raw s_barrier, bf16 P, lacc ones-MFMA, defer-max, balanced qb pairing,
//    per-WAVE block skip (16-row union), fma-folded non-self mask.
//  GEMM2: o @ Wo on 128^2 tiles (GLDS-staged) -> d_out fp32

using bh = __bf16;
typedef __bf16 bhx8 __attribute__((ext_vector_type(8)));
typedef __bf16 bhx4 __attribute__((ext_vector_type(4)));
typedef float  f32x4 __attribute__((ext_vector_type(4)));

#define SEQ   2048
#define HIDN  2048
#define NHEAD 16
#define HDIM  128
#define NBLK  32
#define BLKSZ 64
#define NQKV  6144
#define NGATE 512   // NBLK*NHEAD gate columns
#define LDC   136   // C-tile epilogue stride: 272 B/row = 16B-aligned, 2-way banks (free)
#define PSTRIDE ((size_t)SEQ * NGATE)   // gate partial plane stride

// global -> LDS direct copy, 16 B per lane; LDS dest = wave-uniform base + lane*16
#define GLDS16(gsrc, ldst)                                                     \
  __builtin_amdgcn_global_load_lds(                                            \
      (const __attribute__((address_space(1))) uint32_t*)(gsrc),               \
      (__attribute__((address_space(3))) uint32_t*)(ldst), 16, 0, 0)

// ---------------- split fp32 -> bf16 hi + lo ----------------
__global__ __launch_bounds__(256) void split_f32(const float* __restrict__ in,
                                                 bh* __restrict__ hi, bh* __restrict__ lo, int n) {
  int i = (blockIdx.x * 256 + threadIdx.x) * 4;
  if (i >= n) return;
  float4 v = *(const float4*)(in + i);
  bhx4 h4, l4;
  float vv[4] = {v.x, v.y, v.z, v.w};
#pragma unroll
  for (int e = 0; e < 4; e++) {
    bh h = (bh)vv[e];
    h4[e] = h;
    l4[e] = (bh)(vv[e] - (float)h);
  }
  *(bhx4*)(hi + i) = h4;
  *(bhx4*)(lo + i) = l4;
}

// ---------------- fused transpose + cast for Wq/Wk/Wv/Wo (z = which) ----------------
__global__ __launch_bounds__(256) void transpose_cast4(const float* __restrict__ Wq,
                                                       const float* __restrict__ Wk,
                                                       const float* __restrict__ Wv,
                                                       const float* __restrict__ Wo,
                                                       bh* __restrict__ wqkvT, bh* __restrict__ woT) {
  __shared__ float tile[32][33];
  const int z = blockIdx.z;
  const float* in = (z == 0) ? Wq : (z == 1) ? Wk : (z == 2) ? Wv : Wo;
  bh* out = (z < 3) ? (wqkvT + (size_t)z * HIDN * HIDN) : woT;
  int tx = threadIdx.x, ty = threadIdx.y;
  int c0 = blockIdx.x * 32, r0 = blockIdx.y * 32;
#pragma unroll
  for (int i = 0; i < 4; i++)
    tile[ty + i * 8][tx] = in[(size_t)(r0 + ty + i * 8) * HIDN + c0 + tx];
  __syncthreads();
#pragma unroll
  for (int i = 0; i < 4; i++)
    out[(size_t)(c0 + ty + i * 8) * HIDN + r0 + tx] = (bh)tile[tx][ty + i * 8];
}

// ======== shared GEMM body: 128x128 tile, BK=64, global_load_lds staging ========
// LDS linear [128][64] bf16 per tile; XOR swizzle (byte ^= (row&7)<<4) applied to
// the GLOBAL source at stage time and to the ds_read byte offset (both-sides rule).
#define GEMM_STAGE_TILE(SRC, r0_, ldsbase)                                       \
  {                                                                              \
    _Pragma("unroll")                                                            \
    for (int it_ = 0; it_ < 4; it_++) {                                          \
      int idx_ = it_ * 256 + t;                                                  \
      int row_ = idx_ >> 3, x_ = (idx_ & 7) << 4;                                \
      GLDS16((const char*)(SRC) + (size_t)(r0_ + row_) * strideB + kbyte +       \
                 (x_ ^ ((row_ & 7) << 4)),                                       \
             (char*)(ldsbase) + ((idx_ >> 6) << 10));                            \
    }                                                                            \
  }

// ---------------- GEMM1: bf16 out via LDS restage + uint4 stores ----------------
__global__ __launch_bounds__(256) void gemm_bt(const bh* __restrict__ A, const bh* __restrict__ BT,
                                               bh* __restrict__ Cb, int M, int N, int K) {
  __shared__ __align__(16) bh smem[128 * LDC];   // 34 KB; As/Bs carve 32 KB; epilogue reuses all
  bh* As = smem;                 // [128][64] linear, swizzled
  bh* Bs = smem + 128 * 64;
  const int t = threadIdx.x;
  const int L = t & 63, w = t >> 6;
  const int wm = w & 1, wn = w >> 1;
  const int quad = L >> 4, lo = L & 15;
  const int m0 = blockIdx.y * 128, n0 = blockIdx.x * 128;
  const size_t strideB = (size_t)K * 2;

  f32x4 acc[4][4];
#pragma unroll
  for (int i = 0; i < 4; i++)
#pragma unroll
    for (int j = 0; j < 4; j++) acc[i][j] = (f32x4){0.f, 0.f, 0.f, 0.f};

  for (int k0 = 0; k0 < K; k0 += 64) {
    const size_t kbyte = (size_t)k0 * 2;
    GEMM_STAGE_TILE(A, m0, As);
    GEMM_STAGE_TILE(BT, n0, Bs);
    __syncthreads();               // compiler drains vmcnt(0) before barrier (m97 structure)
#pragma unroll
    for (int ks = 0; ks < 2; ks++) {
      bhx8 af[4], bf_[4];
#pragma unroll
      for (int i = 0; i < 4; i++) {
        const int row = wm * 64 + i * 16 + lo;
        af[i] = *(const bhx8*)((const char*)As + row * 128 +
                               ((ks * 64 + quad * 16) ^ ((row & 7) << 4)));
      }
#pragma unroll
      for (int j = 0; j < 4; j++) {
        const int row = wn * 64 + j * 16 + lo;
        bf_[j] = *(const bhx8*)((const char*)Bs + row * 128 +
                                ((ks * 64 + quad * 16) ^ ((row & 7) << 4)));
      }
#pragma unroll
      for (int i = 0; i < 4; i++)
#pragma unroll
        for (int j = 0; j < 4; j++)
          acc[i][j] = __builtin_amdgcn_mfma_f32_16x16x32_bf16(af[i], bf_[j], acc[i][j], 0, 0, 0);
    }
    __syncthreads();
  }

  // epilogue: scatter acc -> LDS C-tile, then fully-coalesced 16B global stores
  bh* Cs = smem;
#pragma unroll
  for (int i = 0; i < 4; i++)
#pragma unroll
    for (int j = 0; j < 4; j++)
#pragma unroll
      for (int r = 0; r < 4; r++)
        Cs[(wm * 64 + i * 16 + quad * 4 + r) * LDC + wn * 64 + j * 16 + lo] = (bh)acc[i][j][r];
  __syncthreads();
#pragma unroll
  for (int it = 0; it < 8; it++) {
    int idx = it * 256 + t;                 // 2048 chunks: 128 rows x 16
    int row = idx >> 4, cg = idx & 15;
    *(uint4*)(Cb + (size_t)(m0 + row) * N + n0 + cg * 8) = *(const uint4*)&Cs[row * LDC + cg * 8];
  }
}

// ---------------- GEMM: 128^2 tile, fp32 out (o-projection) ----------------
__global__ __launch_bounds__(256) void gemm_bt128f(const bh* __restrict__ A, const bh* __restrict__ BT,
                                                   float* __restrict__ Cf, int M, int N, int K) {
  __shared__ __align__(16) bh smem[2 * 128 * 64];  // 32 KB
  bh* As = smem;
  bh* Bs = smem + 128 * 64;
  const int t = threadIdx.x;
  const int L = t & 63, w = t >> 6;
  const int wm = w & 1, wn = w >> 1;
  const int quad = L >> 4, lo = L & 15;
  const int m0 = blockIdx.y * 128, n0 = blockIdx.x * 128;
  const size_t strideB = (size_t)K * 2;

  f32x4 acc[4][4];
#pragma unroll
  for (int i = 0; i < 4; i++)
#pragma unroll
    for (int j = 0; j < 4; j++) acc[i][j] = (f32x4){0.f, 0.f, 0.f, 0.f};

  for (int k0 = 0; k0 < K; k0 += 64) {
    const size_t kbyte = (size_t)k0 * 2;
    GEMM_STAGE_TILE(A, m0, As);
    GEMM_STAGE_TILE(BT, n0, Bs);
    __syncthreads();
#pragma unroll
    for (int ks = 0; ks < 2; ks++) {
      bhx8 af[4], bf_[4];
#pragma unroll
      for (int i = 0; i < 4; i++) {
        const int row = wm * 64 + i * 16 + lo;
        af[i] = *(const bhx8*)((const char*)As + row * 128 +
                               ((ks * 64 + quad * 16) ^ ((row & 7) << 4)));
      }
#pragma unroll
      for (int j = 0; j < 4; j++) {
        const int row = wn * 64 + j * 16 + lo;
        bf_[j] = *(const bhx8*)((const char*)Bs + row * 128 +
                                ((ks * 64 + quad * 16) ^ ((row & 7) << 4)));
      }
#pragma unroll
      for (int i = 0; i < 4; i++)
#pragma unroll
        for (int j = 0; j < 4; j++)
          acc[i][j] = __builtin_amdgcn_mfma_f32_16x16x32_bf16(af[i], bf_[j], acc[i][j], 0, 0, 0);
    }
    __syncthreads();
  }

  // fp32 stores: 16 lanes x 4 B = full 64 B sectors per quad-row (no amplification)
#pragma unroll
  for (int i = 0; i < 4; i++)
#pragma unroll
    for (int j = 0; j < 4; j++)
#pragma unroll
      for (int r = 0; r < 4; r++) {
        int row = m0 + wm * 64 + i * 16 + quad * 4 + r;
        int col = n0 + wn * 64 + j * 16 + lo;
        Cf[(size_t)row * N + col] = acc[i][j][r];
      }
}

// ---------------- gate GEMM, 6-way split, 128^2 tiles, GLDS-staged ----------------
// z = phase*2 + khalf; phase 0: hi@wgh, 1: lo@wgh, 2: hi@wgl; K=1024 each.
__global__ __launch_bounds__(256) void gemm_gate_split(const bh* __restrict__ hs_hi,
                                                       const bh* __restrict__ hs_lo,
                                                       const bh* __restrict__ wg_hi,
                                                       const bh* __restrict__ wg_lo,
                                                       float* __restrict__ part) {
  __shared__ __align__(16) bh smem[2 * 128 * 64];  // 32 KB
  bh* As = smem;
  bh* Bs = smem + 128 * 64;
  const int t = threadIdx.x;
  const int L = t & 63, w = t >> 6;
  const int wm = w & 1, wn = w >> 1;
  const int quad = L >> 4, lo = L & 15;
  const int m0 = blockIdx.y * 128, n0 = blockIdx.x * 128;
  const int z = blockIdx.z;
  const bh* Ap = ((z >> 1) == 1) ? hs_lo : hs_hi;
  const bh* Bp = ((z >> 1) == 2) ? wg_lo : wg_hi;
  const int kb = (z & 1) * 1024;
  const size_t strideB = (size_t)HIDN * 2;

  f32x4 acc[4][4];
#pragma unroll
  for (int i = 0; i < 4; i++)
#pragma unroll
    for (int j = 0; j < 4; j++) acc[i][j] = (f32x4){0.f, 0.f, 0.f, 0.f};

  for (int k0 = 0; k0 < 1024; k0 += 64) {
    const size_t kbyte = (size_t)(kb + k0) * 2;
    GEMM_STAGE_TILE(Ap, m0, As);
    GEMM_STAGE_TILE(Bp, n0, Bs);
    __syncthreads();
#pragma unroll
    for (int ks = 0; ks < 2; ks++) {
      bhx8 af[4], bf_[4];
#pragma unroll
      for (int i = 0; i < 4; i++) {
        const int row = wm * 64 + i * 16 + lo;
        af[i] = *(const bhx8*)((const char*)As + row * 128 +
                               ((ks * 64 + quad * 16) ^ ((row & 7) << 4)));
      }
#pragma unroll
      for (int j = 0; j < 4; j++) {
        const int row = wn * 64 + j * 16 + lo;
        bf_[j] = *(const bhx8*)((const char*)Bs + row * 128 +
                                ((ks * 64 + quad * 16) ^ ((row & 7) << 4)));
      }
#pragma unroll
      for (int i = 0; i < 4; i++)
#pragma unroll
        for (int j = 0; j < 4; j++)
          acc[i][j] = __builtin_amdgcn_mfma_f32_16x16x32_bf16(af[i], bf_[j], acc[i][j], 0, 0, 0);
    }
    __syncthreads();
  }

#pragma unroll
  for (int i = 0; i < 4; i++)
#pragma unroll
    for (int j = 0; j < 4; j++)
#pragma unroll
      for (int r = 0; r < 4; r++) {
        int row = m0 + wm * 64 + i * 16 + quad * 4 + r;
        int col = n0 + wn * 64 + j * 16 + lo;
        part[(size_t)z * PSTRIDE + (size_t)row * NGATE + col] = acc[i][j][r];
      }
}

// ---------------- hsmean: block-mean of hs fp32 -> [NBLK][HIDN] ----------------
__global__ __launch_bounds__(256) void hsmean_k(const float* __restrict__ hs, float* __restrict__ hsm) {
  int idx = blockIdx.x * 256 + threadIdx.x;   // 65536
  int n = idx >> 11, c = idx & 2047;
  const float* p = hs + (size_t)(n * BLKSZ) * HIDN + c;
  float s = 0.f;
#pragma unroll 8
  for (int r = 0; r < BLKSZ; r++) s += p[(size_t)r * HIDN];
  hsm[idx] = s * (1.0f / 64.0f);
}

// ---------------- kg partial: hsm @ Wk fp32, split-K ----------------
__global__ __launch_bounds__(256) void kg_partial(const float* __restrict__ hsm,
                                                  const float* __restrict__ Wk,
                                                  float* __restrict__ part) {
  __shared__ float hl[32][256];
  int c = blockIdx.x * 256 + threadIdx.x;
  int k0 = blockIdx.y * 256;
#pragma unroll 4
  for (int i = 0; i < 32; i++) hl[i][threadIdx.x] = hsm[(size_t)i * HIDN + k0 + threadIdx.x];
  __syncthreads();
  float acc[32];
#pragma unroll
  for (int n = 0; n < 32; n++) acc[n] = 0.f;
  for (int k4 = 0; k4 < 64; k4++) {
    float w0 = Wk[(size_t)(k0 + k4 * 4 + 0) * HIDN + c];
    float w1 = Wk[(size_t)(k0 + k4 * 4 + 1) * HIDN + c];
    float w2 = Wk[(size_t)(k0 + k4 * 4 + 2) * HIDN + c];
    float w3 = Wk[(size_t)(k0 + k4 * 4 + 3) * HIDN + c];
#pragma unroll
    for (int n = 0; n < 32; n++) {
      float4 hv = *(const float4*)&hl[n][k4 * 4];
      acc[n] += hv.x * w0 + hv.y * w1 + hv.z * w2 + hv.w * w3;
    }
  }
#pragma unroll
  for (int n = 0; n < 32; n++)
    part[((size_t)blockIdx.y * 32 + n) * HIDN + c] = acc[n];
}

__global__ __launch_bounds__(256) void kg_reduce8(const float* __restrict__ part, float* __restrict__ kg) {
  int idx = blockIdx.x * 256 + threadIdx.x;   // 65536
  float s = 0.f;
#pragma unroll
  for (int kc = 0; kc < 8; kc++) s += part[(size_t)kc * 65536 + idx];
  kg[idx] = s;
}

// ---------------- wg[(h*32+n)][r] = sum_d Wq[r][h*128+d] * kg[n][h*128+d] (fp32) ----------------
__global__ __launch_bounds__(256) void wg_k(const float* __restrict__ Wq, const float* __restrict__ kg,
                                            float* __restrict__ wg) {
  __shared__ float kl[32][128];
  int h = blockIdx.y;
  int r = blockIdx.x * 256 + threadIdx.x;
  for (int i = threadIdx.x; i < 32 * 128; i += 256)
    kl[i >> 7][i & 127] = kg[(size_t)(i >> 7) * HIDN + h * HDIM + (i & 127)];
  __syncthreads();
  float acc[32];
#pragma unroll
  for (int n = 0; n < 32; n++) acc[n] = 0.f;
  const float4* wrow = (const float4*)(Wq + (size_t)r * HIDN + h * HDIM);
  for (int d4 = 0; d4 < 32; d4++) {
    float4 w = wrow[d4];
#pragma unroll
    for (int n = 0; n < 32; n++) {
      float4 kv = *(const float4*)&kl[n][d4 * 4];
      acc[n] += w.x * kv.x + w.y * kv.y + w.z * kv.z + w.w * kv.w;
    }
  }
#pragma unroll
  for (int n = 0; n < 32; n++)
    wg[(size_t)(h * 32 + n) * HIDN + r] = acc[n];
}

// ---------------- gate + top-8 -> 32-bit block mask per (h,s) ----------------
__global__ __launch_bounds__(256) void gate_topk(const float* __restrict__ part,
                                                 unsigned* __restrict__ bsel) {
  int w = threadIdx.x >> 6, L = threadIdx.x & 63;
  int p = blockIdx.x * 4 + w;               // p = h*2048 + s
  int h = p >> 11, s = p & 2047;
  int qb = s >> 6;
  int n = L;
  float g = -1e30f;
  if (n == qb) g = 1e30f;
  else if (n < qb) {
    size_t off = (size_t)s * NGATE + h * 32 + n;
    g = part[off] + part[off + PSTRIDE] + part[off + 2 * PSTRIDE] +
        part[off + 3 * PSTRIDE] + part[off + 4 * PSTRIDE] + part[off + 5 * PSTRIDE];
  }
  int rank = 0;
#pragma unroll
  for (int j = 0; j < 32; j++) {
    float gj = __shfl(g, j, 64);
    if (gj > g || (gj == g && j < n)) rank++;
  }
  bool sel = (n <= qb) && (n < 32) && (rank < 8);
  unsigned long long bm = __ballot(sel);
  if (L == 0) bsel[p] = (unsigned)(bm & 0xffffffffull);
}

// ---------------- V^T per head: vt[h][d][s] ----------------
__global__ __launch_bounds__(256) void vtrans(const bh* __restrict__ qkv, bh* __restrict__ vt) {
  __shared__ float tile[32][33];
  int tx = threadIdx.x, ty = threadIdx.y;
  int s0 = blockIdx.x * 32, d0 = blockIdx.y * 32, h = blockIdx.z;
#pragma unroll
  for (int i = 0; i < 4; i++)
    tile[ty + i * 8][tx] = (float)qkv[(size_t)(s0 + ty + i * 8) * NQKV + 2 * HIDN + h * HDIM + d0 + tx];
  __syncthreads();
#pragma unroll
  for (int i = 0; i < 4; i++)
    vt[((size_t)h * HDIM + d0 + ty + i * 8) * SEQ + s0 + tx] = (bh)tile[tx][ty + i * 8];
}

// ---------------- attn v5: 1 workgroup (4 waves) per (h, 64-row q-block) ----------------
// dbuf K/V via global_load_lds + XOR swizzle, counted vmcnt(8) + raw s_barrier,
// per-wave block skip (16-row union), fma-folded non-self mask.
__global__ __launch_bounds__(256) void attn(const bh* __restrict__ qkv, const bh* __restrict__ vt,
                                            const unsigned* __restrict__ bsel, bh* __restrict__ obuf) {
  __shared__ __align__(16) bh Ksm[2][64 * 128];   // 2 x 16 KB, linear 256 B rows, XOR-swizzled
  __shared__ __align__(16) bh Vsm[2][128 * 64];   // 2 x 16 KB, linear 128 B rows, XOR-swizzled
  __shared__ __align__(16) bh PLb[4][16 * 72];    // bf16 P, 144 B rows (16B-aligned, 2-way banks)
  __shared__ unsigned ublk;
  const int t = threadIdx.x;
  const int w = t >> 6, L = t & 63;
  const int quad = L >> 4, lo = L & 15;
  // XCD-aware remap: bid&7 = XCD -> 2 heads per XCD (K/V ~2MB fits 4MB L2).
  // Balanced pairing: jj<32 heavy (qb 31..16, dispatched first), jj>=32 light.
  const int bid = blockIdx.x;
  const int jj = bid >> 3;
  const int h = ((bid & 7) << 1) | (jj & 1);
  const int qb = (jj < 32) ? (31 - (jj >> 1)) : ((jj - 32) >> 1);
  const int s0 = qb * 64 + w * 16;

  unsigned bs[4];
#pragma unroll
  for (int r = 0; r < 4; r++) bs[r] = bsel[h * SEQ + s0 + quad * 4 + r];
  unsigned uni = bs[0] | bs[1] | bs[2] | bs[3];
  uni |= (unsigned)__shfl_xor((int)uni, 16);
  uni |= (unsigned)__shfl_xor((int)uni, 32);
  const unsigned uniw = uni;                 // this wave's 16-row union
  if (t == 0) ublk = 0;
  __syncthreads();
  if (L == 0) atomicOr(&ublk, uni);
  __syncthreads();
  const unsigned un = ublk;                  // WG-level union (drives staging loop)

  bhx8 aq[4];
  const bh* qrow = qkv + (size_t)(s0 + lo) * NQKV + h * HDIM;
#pragma unroll
  for (int ks = 0; ks < 4; ks++) aq[ks] = *(const bhx8*)(qrow + ks * 32 + quad * 8);

  f32x4 oacc[8];
#pragma unroll
  for (int j = 0; j < 8; j++) oacc[j] = (f32x4){0.f, 0.f, 0.f, 0.f};
  f32x4 lacc = (f32x4){0.f, 0.f, 0.f, 0.f};       // row-sum accumulator (== li)
  float mi[4] = {-1e30f, -1e30f, -1e30f, -1e30f};

  bhx8 ones8;
#pragma unroll
  for (int e = 0; e < 8; e++) ones8[e] = (bh)1.0f;

  const float scale = 0.08838834764831845f;  // 1/sqrt(128)

  // stage K tile (64 rows x 256 B) + V tile (128 rows x 128 B) for block n into buffer b.
  auto stageKV = [&](int b, int n) {
    const char* ksrc = (const char*)(qkv + (size_t)(n * BLKSZ) * NQKV + HIDN + h * HDIM);
    const char* vsrc = (const char*)(vt + ((size_t)h * HDIM) * SEQ + n * BLKSZ);
    char* kb = (char*)&Ksm[b][0];
    char* vb = (char*)&Vsm[b][0];
#pragma unroll
    for (int it = 0; it < 4; it++) {
      int idx = it * 256 + t;                 // 1024 chunks of 16 B: row = idx>>4
      int row = idx >> 4, x = (idx & 15) << 4;
      GLDS16(ksrc + (size_t)row * (NQKV * 2) + (x ^ ((row & 7) << 4)),
             kb + ((idx >> 6) << 10));        // wave-uniform base; HW adds lane*16
    }
#pragma unroll
    for (int it = 0; it < 4; it++) {
      int idx = it * 256 + t;                 // 1024 chunks of 16 B: row = idx>>3
      int row = idx >> 3, x = (idx & 7) << 4;
      GLDS16(vsrc + (size_t)row * (SEQ * 2) + (x ^ ((row & 7) << 4)),
             vb + ((idx >> 6) << 10));
    }
  };

  unsigned rem = un;                          // un != 0 (self block always set)
  int ncur = (int)__builtin_ctz(rem);
  rem &= rem - 1;
  stageKV(0, ncur);
  int cur = 0;

  while (true) {
    int nnext = -1;
    if (rem) { nnext = (int)__builtin_ctz(rem); rem &= rem - 1; }
    if (nnext >= 0) {
      stageKV(cur ^ 1, nnext);
      // 8 newest outstanding = next-tile loads; wait only for current tile (+Q).
      asm volatile("s_waitcnt vmcnt(8)" ::: "memory");
    } else {
      asm volatile("s_waitcnt vmcnt(0)" ::: "memory");
    }
    __builtin_amdgcn_s_barrier();

    // per-wave skip: none of this wave's 16 rows selected block ncur ->
    // its contribution is all-masked zeros; skip compute, keep barriers.
    if ((uniw >> ncur) & 1) {
      const char* Kc = (const char*)&Ksm[cur][0];
      const char* Vc = (const char*)&Vsm[cur][0];
      const bool self = (ncur == qb);

      f32x4 sc[4];
      __builtin_amdgcn_s_setprio(1);
#pragma unroll
      for (int nt = 0; nt < 4; nt++) {
        f32x4 s4 = (f32x4){0.f, 0.f, 0.f, 0.f};
#pragma unroll
        for (int ks = 0; ks < 4; ks++) {
          const int row = nt * 16 + lo;
          bhx8 bk = *(const bhx8*)(Kc + row * 256 + ((ks * 64 + quad * 16) ^ ((row & 7) << 4)));
          s4 = __builtin_amdgcn_mfma_f32_16x16x32_bf16(aq[ks], bk, s4, 0, 0, 0);
        }
        sc[nt] = s4;
      }
      __builtin_amdgcn_s_setprio(0);

      if (self) {
#pragma unroll
        for (int nt = 0; nt < 4; nt++)
#pragma unroll
          for (int r = 0; r < 4; r++) {
            float v = sc[nt][r] * scale;
            int kpos = ncur * BLKSZ + nt * 16 + lo;
            int qpos = s0 + quad * 4 + r;
            bool ok = ((bs[r] >> ncur) & 1) && (kpos <= qpos);
            sc[nt][r] = ok ? v : -1e30f;
          }
      } else {
        float bias[4];
#pragma unroll
        for (int r = 0; r < 4; r++)
          bias[r] = ((bs[r] >> ncur) & 1) ? 0.f : -1e30f;
#pragma unroll
        for (int nt = 0; nt < 4; nt++)
#pragma unroll
          for (int r = 0; r < 4; r++)
            sc[nt][r] = sc[nt][r] * scale + bias[r];
      }
      float rm[4];
#pragma unroll
      for (int r = 0; r < 4; r++)
        rm[r] = fmaxf(fmaxf(sc[0][r], sc[1][r]), fmaxf(sc[2][r], sc[3][r]));
#pragma unroll
      for (int off = 1; off < 16; off <<= 1)
#pragma unroll
        for (int r = 0; r < 4; r++) rm[r] = fmaxf(rm[r], __shfl_xor(rm[r], off));

      // defer-max (T13, THR=8): rescale only when the running max grew enough.
      bool exceed = (rm[0] > mi[0] + 8.f) || (rm[1] > mi[1] + 8.f) ||
                    (rm[2] > mi[2] + 8.f) || (rm[3] > mi[3] + 8.f);
      if (__any(exceed)) {
        float alpha[4];
#pragma unroll
        for (int r = 0; r < 4; r++) {
          float nm = fmaxf(mi[r], rm[r]);
          alpha[r] = __expf(mi[r] - nm);
          mi[r] = nm;
        }
#pragma unroll
        for (int j = 0; j < 8; j++)
#pragma unroll
          for (int r = 0; r < 4; r++) oacc[j][r] *= alpha[r];
#pragma unroll
        for (int r = 0; r < 4; r++) lacc[r] *= alpha[r];
      }

#pragma unroll
      for (int nt = 0; nt < 4; nt++)
#pragma unroll
        for (int r = 0; r < 4; r++) {
          float sv = sc[nt][r];
          float pv = (sv > -1e29f) ? __expf(sv - mi[r]) : 0.f;
          PLb[w][(quad * 4 + r) * 72 + nt * 16 + lo] = (bh)pv;   // per-wave slab
        }

      __builtin_amdgcn_s_setprio(1);
#pragma unroll
      for (int kk = 0; kk < 2; kk++) {
        bhx8 pa = *(const bhx8*)&PLb[w][lo * 72 + kk * 32 + quad * 8];
        // all-ones B: every output column = row-sum of P -> lacc tracks li for free
        lacc = __builtin_amdgcn_mfma_f32_16x16x32_bf16(pa, ones8, lacc, 0, 0, 0);
#pragma unroll
        for (int j = 0; j < 8; j++) {
          const int row = j * 16 + lo;
          bhx8 vv = *(const bhx8*)(Vc + row * 128 + ((kk * 64 + quad * 16) ^ ((row & 7) << 4)));
          oacc[j] = __builtin_amdgcn_mfma_f32_16x16x32_bf16(pa, vv, oacc[j], 0, 0, 0);
        }
      }
      __builtin_amdgcn_s_setprio(0);
    }

    __builtin_amdgcn_s_barrier();   // all waves done reading buf[cur] before it is restaged
    if (nnext < 0) break;
    ncur = nnext;
    cur ^= 1;
  }

#pragma unroll
  for (int j = 0; j < 8; j++)
#pragma unroll
    for (int r = 0; r < 4; r++) {
      int row = s0 + quad * 4 + r;
      int col = h * HDIM + j * 16 + lo;
      obuf[(size_t)row * HIDN + col] = (bh)(oacc[j][r] / lacc[r]);
    }
}

// ---------------- launch ----------------
extern "C" void kernel_launch(void* const* d_in, const int* in_sizes, int n_in,
                              void* d_out, int out_size, void* d_ws, size_t ws_size,
                              hipStream_t stream) {
  const float* hs = (const float*)d_in[0];
  const float* Wq = (const float*)d_in[1];
  const float* Wk = (const float*)d_in[2];
  const float* Wv = (const float*)d_in[3];
  const float* Wo = (const float*)d_in[4];

  char* ws = (char*)d_ws;
  bh* hs_hi = (bh*)ws;            ws += (size_t)SEQ * HIDN * 2;         // 8 MB
  bh* hs_lo = (bh*)ws;            ws += (size_t)SEQ * HIDN * 2;         // 8 MB
  bh* wqkvT = (bh*)ws;            ws += (size_t)NQKV * HIDN * 2;        // 24 MB
  bh* woT = (bh*)ws;              ws += (size_t)HIDN * HIDN * 2;        // 8 MB
  bh* qkv = (bh*)ws;              ws += (size_t)SEQ * NQKV * 2;         // 24 MB
  bh* vt = (bh*)ws;               ws += (size_t)NHEAD * HDIM * SEQ * 2; // 8 MB
  bh* obuf = (bh*)ws;             ws += (size_t)SEQ * HIDN * 2;         // 8 MB
  float* hsm = (float*)ws;        ws += (size_t)NBLK * HIDN * 4;        // 256 KB
  float* kg_part = (float*)ws;    ws += (size_t)8 * NBLK * HIDN * 4;    // 2 MB
  float* kg = (float*)ws;         ws += (size_t)NBLK * HIDN * 4;        // 256 KB
  float* wg = (float*)ws;         ws += (size_t)NGATE * HIDN * 4;       // 4 MB
  bh* wg_hi = (bh*)ws;            ws += (size_t)NGATE * HIDN * 2;       // 2 MB
  bh* wg_lo = (bh*)ws;            ws += (size_t)NGATE * HIDN * 2;       // 2 MB
  unsigned* bsel = (unsigned*)ws; ws += (size_t)NHEAD * SEQ * 4;        // 128 KB
  // gate partials (6 x 4 MB = 24 MB) alias wqkvT (24 MB): wqkvT is dead after
  // the qkv GEMM, and the stream serializes gemm_bt -> gemm_gate_split.
  float* gpart = (float*)wqkvT;

  // hs split + fused weight transposes
  split_f32<<<(SEQ * HIDN) / 1024, 256, 0, stream>>>(hs, hs_hi, hs_lo, SEQ * HIDN);
  transpose_cast4<<<dim3(64, 64, 4), dim3(32, 8), 0, stream>>>(Wq, Wk, Wv, Wo, wqkvT, woT);

  // qkv bf16
  gemm_bt<<<dim3(NQKV / 128, SEQ / 128), 256, 0, stream>>>(hs_hi, wqkvT, qkv, SEQ, NQKV, HIDN);

  // fp32 gate path (wqkvT dead from here; gpart aliases it)
  hsmean_k<<<(NBLK * HIDN) / 256, 256, 0, stream>>>(hs, hsm);
  kg_partial<<<dim3(8, 8), 256, 0, stream>>>(hsm, Wk, kg_part);
  kg_reduce8<<<(NBLK * HIDN) / 256, 256, 0, stream>>>(kg_part, kg);
  wg_k<<<dim3(8, NHEAD), 256, 0, stream>>>(Wq, kg, wg);
  split_f32<<<(NGATE * HIDN) / 1024, 256, 0, stream>>>(wg, wg_hi, wg_lo, NGATE * HIDN);
  gemm_gate_split<<<dim3(NGATE / 128, SEQ / 128, 6), 256, 0, stream>>>(hs_hi, hs_lo, wg_hi, wg_lo, gpart);
  gate_topk<<<(NHEAD * SEQ) / 4, 256, 0, stream>>>(gpart, bsel);

  // attention (1D grid, XCD-aware remap inside the kernel)
  vtrans<<<dim3(SEQ / 32, HDIM / 32, NHEAD), dim3(32, 8), 0, stream>>>(qkv, vt);
  attn<<<dim3(NBLK * NHEAD), 256, 0, stream>>>(qkv, vt, bsel, obuf);

  // output projection (128x128 tiles -> 256 blocks = full CU fill)
  gemm_bt128f<<<dim3(HIDN / 128, SEQ / 128), 256, 0, stream>>>(obuf, woT, (float*)d_out, SEQ, HIDN, HIDN);
}

// Round 7
// 421.073 us; speedup vs baseline: 1.4350x; 1.1144x over previous
//
#include <hip/hip_runtime.h>
#include <hip/hip_bf16.h>
#include <stdint.h>
#include <stddef.h>

// MoBA forward, MI355X.
//  split hs -> bf16 hi/lo; transpose-cast W's -> B^T bf16 (fused 4-in-1)
//  qkvkg MEGA: GEMM1 (qkv, GLDS-staged 128^2) blocks 0..767  UNION
//              kg partial (hsm @ Wk fp32, 512 latency-hiding blocks) 768..1279
//  fp32 gate path: kg_reduce64 -> wg = Wq_h @ kg_h (fp32)
//    gate partials = bf16x3 MFMA split 6 ways, 128^2 tiles, GLDS-staged
//  gate_topk: sums 6 partials, rank-based top-8 -> 32-bit block mask
//  attn v6: dbuf K/V via global_load_lds + XOR swizzle, counted vmcnt(8) +
//    raw s_barrier, bf16 P, lacc ones-MFMA, defer-max, balanced qb pairing,
//    per-WAVE block skip, fma-folded mask, guard-free exp.
//  GEMM2: o @ Wo on 128^2 tiles (GLDS-staged) -> d_out fp32
//  WS NOTE (round-7 fix): kg_part (16 MB) ALIASES vt+obuf (dead until
//  vtrans/attn) -> explicit workspace stays at 96.6 MB (round-5 passing level).

using bh = __bf16;
typedef __bf16 bhx8 __attribute__((ext_vector_type(8)));
typedef __bf16 bhx4 __attribute__((ext_vector_type(4)));
typedef float  f32x4 __attribute__((ext_vector_type(4)));

#define SEQ   2048
#define HIDN  2048
#define NHEAD 16
#define HDIM  128
#define NBLK  32
#define BLKSZ 64
#define NQKV  6144
#define NGATE 512   // NBLK*NHEAD gate columns
#define LDC   136   // C-tile epilogue stride: 272 B/row = 16B-aligned, 2-way banks (free)
#define PSTRIDE ((size_t)SEQ * NGATE)   // gate partial plane stride

// global -> LDS direct copy, 16 B per lane; LDS dest = wave-uniform base + lane*16
#define GLDS16(gsrc, ldst)                                                     \
  __builtin_amdgcn_global_load_lds(                                            \
      (const __attribute__((address_space(1))) uint32_t*)(gsrc),               \
      (__attribute__((address_space(3))) uint32_t*)(ldst), 16, 0, 0)

// ---------------- split fp32 -> bf16 hi + lo ----------------
__global__ __launch_bounds__(256) void split_f32(const float* __restrict__ in,
                                                 bh* __restrict__ hi, bh* __restrict__ lo, int n) {
  int i = (blockIdx.x * 256 + threadIdx.x) * 4;
  if (i >= n) return;
  float4 v = *(const float4*)(in + i);
  bhx4 h4, l4;
  float vv[4] = {v.x, v.y, v.z, v.w};
#pragma unroll
  for (int e = 0; e < 4; e++) {
    bh h = (bh)vv[e];
    h4[e] = h;
    l4[e] = (bh)(vv[e] - (float)h);
  }
  *(bhx4*)(hi + i) = h4;
  *(bhx4*)(lo + i) = l4;
}

// ---------------- fused transpose + cast for Wq/Wk/Wv/Wo (z = which) ----------------
__global__ __launch_bounds__(256) void transpose_cast4(const float* __restrict__ Wq,
                                                       const float* __restrict__ Wk,
                                                       const float* __restrict__ Wv,
                                                       const float* __restrict__ Wo,
                                                       bh* __restrict__ wqkvT, bh* __restrict__ woT) {
  __shared__ float tile[32][33];
  const int z = blockIdx.z;
  const float* in = (z == 0) ? Wq : (z == 1) ? Wk : (z == 2) ? Wv : Wo;
  bh* out = (z < 3) ? (wqkvT + (size_t)z * HIDN * HIDN) : woT;
  int tx = threadIdx.x, ty = threadIdx.y;
  int c0 = blockIdx.x * 32, r0 = blockIdx.y * 32;
#pragma unroll
  for (int i = 0; i < 4; i++)
    tile[ty + i * 8][tx] = in[(size_t)(r0 + ty + i * 8) * HIDN + c0 + tx];
  __syncthreads();
#pragma unroll
  for (int i = 0; i < 4; i++)
    out[(size_t)(c0 + ty + i * 8) * HIDN + r0 + tx] = (bh)tile[tx][ty + i * 8];
}

// ======== shared GEMM staging: 128x128 tile, BK=64, global_load_lds ========
// LDS linear [128][64] bf16 per tile; XOR swizzle (byte ^= (row&7)<<4) applied to
// the GLOBAL source at stage time and to the ds_read byte offset (both-sides rule).
#define GEMM_STAGE_TILE(SRC, r0_, ldsbase)                                       \
  {                                                                              \
    _Pragma("unroll")                                                            \
    for (int it_ = 0; it_ < 4; it_++) {                                          \
      int idx_ = it_ * 256 + t;                                                  \
      int row_ = idx_ >> 3, x_ = (idx_ & 7) << 4;                                \
      GLDS16((const char*)(SRC) + (size_t)(r0_ + row_) * strideB + kbyte +       \
                 (x_ ^ ((row_ & 7) << 4)),                                       \
             (char*)(ldsbase) + ((idx_ >> 6) << 10));                            \
    }                                                                            \
  }

// ---------------- MEGA: qkv GEMM (blocks 0..767) UNION kg partial (768..1279) ----------------
// qkv: Cb[SEQ][NQKV] = A[SEQ][HIDN] * BT[NQKV][HIDN]^T, bf16 out via LDS restage.
// kg:  part[ky][n][c] = sum_{k in 32-chunk ky} hsm[n][k] * Wk[k][c]  (fp32)
__global__ __launch_bounds__(256) void qkvkg(const bh* __restrict__ A, const bh* __restrict__ BT,
                                             bh* __restrict__ Cb,
                                             const float* __restrict__ hsm,
                                             const float* __restrict__ Wk,
                                             float* __restrict__ part) {
  __shared__ __align__(16) char smraw[128 * LDC * 2];   // 34816 B, union of both branches
  const int t = threadIdx.x;

  if (blockIdx.x < 768) {
    // ---- qkv GEMM tile ----
    bh* smem = (bh*)smraw;
    bh* As = smem;                 // [128][64] linear, swizzled
    bh* Bs = smem + 128 * 64;
    const int L = t & 63, w = t >> 6;
    const int wm = w & 1, wn = w >> 1;
    const int quad = L >> 4, lo = L & 15;
    const int m0 = (blockIdx.x / 48) * 128, n0 = (blockIdx.x % 48) * 128;
    const size_t strideB = (size_t)HIDN * 2;

    f32x4 acc[4][4];
#pragma unroll
    for (int i = 0; i < 4; i++)
#pragma unroll
      for (int j = 0; j < 4; j++) acc[i][j] = (f32x4){0.f, 0.f, 0.f, 0.f};

    for (int k0 = 0; k0 < HIDN; k0 += 64) {
      const size_t kbyte = (size_t)k0 * 2;
      GEMM_STAGE_TILE(A, m0, As);
      GEMM_STAGE_TILE(BT, n0, Bs);
      __syncthreads();
#pragma unroll
      for (int ks = 0; ks < 2; ks++) {
        bhx8 af[4], bf_[4];
#pragma unroll
        for (int i = 0; i < 4; i++) {
          const int row = wm * 64 + i * 16 + lo;
          af[i] = *(const bhx8*)((const char*)As + row * 128 +
                                 ((ks * 64 + quad * 16) ^ ((row & 7) << 4)));
        }
#pragma unroll
        for (int j = 0; j < 4; j++) {
          const int row = wn * 64 + j * 16 + lo;
          bf_[j] = *(const bhx8*)((const char*)Bs + row * 128 +
                                  ((ks * 64 + quad * 16) ^ ((row & 7) << 4)));
        }
#pragma unroll
        for (int i = 0; i < 4; i++)
#pragma unroll
          for (int j = 0; j < 4; j++)
            acc[i][j] = __builtin_amdgcn_mfma_f32_16x16x32_bf16(af[i], bf_[j], acc[i][j], 0, 0, 0);
      }
      __syncthreads();
    }

    // epilogue: scatter acc -> LDS C-tile, then fully-coalesced 16B global stores
    bh* Cs = smem;
#pragma unroll
    for (int i = 0; i < 4; i++)
#pragma unroll
      for (int j = 0; j < 4; j++)
#pragma unroll
        for (int r = 0; r < 4; r++)
          Cs[(wm * 64 + i * 16 + quad * 4 + r) * LDC + wn * 64 + j * 16 + lo] = (bh)acc[i][j][r];
    __syncthreads();
#pragma unroll
    for (int it = 0; it < 8; it++) {
      int idx = it * 256 + t;                 // 2048 chunks: 128 rows x 16
      int row = idx >> 4, cg = idx & 15;
      *(uint4*)(Cb + (size_t)(m0 + row) * NQKV + n0 + cg * 8) = *(const uint4*)&Cs[row * LDC + cg * 8];
    }
  } else {
    // ---- kg partial: 512 blocks (8 c-chunks x 64 k-chunks), high occupancy ----
    float (*hl)[32] = (float (*)[32])smraw;   // hsm[32 n][32 k] slice, 4 KB
    const int b2 = blockIdx.x - 768;
    const int c = (b2 & 7) * 256 + t;
    const int ky = b2 >> 3;
    const int k0 = ky * 32;
    for (int i = t; i < 32 * 32; i += 256)
      hl[i >> 5][i & 31] = hsm[(size_t)(i >> 5) * HIDN + k0 + (i & 31)];
    __syncthreads();
    float acc[32];
#pragma unroll
    for (int n = 0; n < 32; n++) acc[n] = 0.f;
#pragma unroll 2
    for (int k4 = 0; k4 < 8; k4++) {
      float w0 = Wk[(size_t)(k0 + k4 * 4 + 0) * HIDN + c];
      float w1 = Wk[(size_t)(k0 + k4 * 4 + 1) * HIDN + c];
      float w2 = Wk[(size_t)(k0 + k4 * 4 + 2) * HIDN + c];
      float w3 = Wk[(size_t)(k0 + k4 * 4 + 3) * HIDN + c];
#pragma unroll
      for (int n = 0; n < 32; n++) {
        float4 hv = *(const float4*)&hl[n][k4 * 4];
        acc[n] += hv.x * w0 + hv.y * w1 + hv.z * w2 + hv.w * w3;
      }
    }
#pragma unroll
    for (int n = 0; n < 32; n++)
      part[((size_t)ky * 32 + n) * HIDN + c] = acc[n];
  }
}

// ---------------- GEMM: 128^2 tile, fp32 out (o-projection) ----------------
__global__ __launch_bounds__(256) void gemm_bt128f(const bh* __restrict__ A, const bh* __restrict__ BT,
                                                   float* __restrict__ Cf, int M, int N, int K) {
  __shared__ __align__(16) bh smem[2 * 128 * 64];  // 32 KB
  bh* As = smem;
  bh* Bs = smem + 128 * 64;
  const int t = threadIdx.x;
  const int L = t & 63, w = t >> 6;
  const int wm = w & 1, wn = w >> 1;
  const int quad = L >> 4, lo = L & 15;
  const int m0 = blockIdx.y * 128, n0 = blockIdx.x * 128;
  const size_t strideB = (size_t)K * 2;

  f32x4 acc[4][4];
#pragma unroll
  for (int i = 0; i < 4; i++)
#pragma unroll
    for (int j = 0; j < 4; j++) acc[i][j] = (f32x4){0.f, 0.f, 0.f, 0.f};

  for (int k0 = 0; k0 < K; k0 += 64) {
    const size_t kbyte = (size_t)k0 * 2;
    GEMM_STAGE_TILE(A, m0, As);
    GEMM_STAGE_TILE(BT, n0, Bs);
    __syncthreads();
#pragma unroll
    for (int ks = 0; ks < 2; ks++) {
      bhx8 af[4], bf_[4];
#pragma unroll
      for (int i = 0; i < 4; i++) {
        const int row = wm * 64 + i * 16 + lo;
        af[i] = *(const bhx8*)((const char*)As + row * 128 +
                               ((ks * 64 + quad * 16) ^ ((row & 7) << 4)));
      }
#pragma unroll
      for (int j = 0; j < 4; j++) {
        const int row = wn * 64 + j * 16 + lo;
        bf_[j] = *(const bhx8*)((const char*)Bs + row * 128 +
                                ((ks * 64 + quad * 16) ^ ((row & 7) << 4)));
      }
#pragma unroll
      for (int i = 0; i < 4; i++)
#pragma unroll
        for (int j = 0; j < 4; j++)
          acc[i][j] = __builtin_amdgcn_mfma_f32_16x16x32_bf16(af[i], bf_[j], acc[i][j], 0, 0, 0);
    }
    __syncthreads();
  }

  // fp32 stores: 16 lanes x 4 B = full 64 B sectors per quad-row (no amplification)
#pragma unroll
  for (int i = 0; i < 4; i++)
#pragma unroll
    for (int j = 0; j < 4; j++)
#pragma unroll
      for (int r = 0; r < 4; r++) {
        int row = m0 + wm * 64 + i * 16 + quad * 4 + r;
        int col = n0 + wn * 64 + j * 16 + lo;
        Cf[(size_t)row * N + col] = acc[i][j][r];
      }
}

// ---------------- gate GEMM, 6-way split, 128^2 tiles, GLDS-staged ----------------
// z = phase*2 + khalf; phase 0: hi@wgh, 1: lo@wgh, 2: hi@wgl; K=1024 each.
__global__ __launch_bounds__(256) void gemm_gate_split(const bh* __restrict__ hs_hi,
                                                       const bh* __restrict__ hs_lo,
                                                       const bh* __restrict__ wg_hi,
                                                       const bh* __restrict__ wg_lo,
                                                       float* __restrict__ part) {
  __shared__ __align__(16) bh smem[2 * 128 * 64];  // 32 KB
  bh* As = smem;
  bh* Bs = smem + 128 * 64;
  const int t = threadIdx.x;
  const int L = t & 63, w = t >> 6;
  const int wm = w & 1, wn = w >> 1;
  const int quad = L >> 4, lo = L & 15;
  const int m0 = blockIdx.y * 128, n0 = blockIdx.x * 128;
  const int z = blockIdx.z;
  const bh* Ap = ((z >> 1) == 1) ? hs_lo : hs_hi;
  const bh* Bp = ((z >> 1) == 2) ? wg_lo : wg_hi;
  const int kb = (z & 1) * 1024;
  const size_t strideB = (size_t)HIDN * 2;

  f32x4 acc[4][4];
#pragma unroll
  for (int i = 0; i < 4; i++)
#pragma unroll
    for (int j = 0; j < 4; j++) acc[i][j] = (f32x4){0.f, 0.f, 0.f, 0.f};

  for (int k0 = 0; k0 < 1024; k0 += 64) {
    const size_t kbyte = (size_t)(kb + k0) * 2;
    GEMM_STAGE_TILE(Ap, m0, As);
    GEMM_STAGE_TILE(Bp, n0, Bs);
    __syncthreads();
#pragma unroll
    for (int ks = 0; ks < 2; ks++) {
      bhx8 af[4], bf_[4];
#pragma unroll
      for (int i = 0; i < 4; i++) {
        const int row = wm * 64 + i * 16 + lo;
        af[i] = *(const bhx8*)((const char*)As + row * 128 +
                               ((ks * 64 + quad * 16) ^ ((row & 7) << 4)));
      }
#pragma unroll
      for (int j = 0; j < 4; j++) {
        const int row = wn * 64 + j * 16 + lo;
        bf_[j] = *(const bhx8*)((const char*)Bs + row * 128 +
                                ((ks * 64 + quad * 16) ^ ((row & 7) << 4)));
      }
#pragma unroll
      for (int i = 0; i < 4; i++)
#pragma unroll
        for (int j = 0; j < 4; j++)
          acc[i][j] = __builtin_amdgcn_mfma_f32_16x16x32_bf16(af[i], bf_[j], acc[i][j], 0, 0, 0);
    }
    __syncthreads();
  }

#pragma unroll
  for (int i = 0; i < 4; i++)
#pragma unroll
    for (int j = 0; j < 4; j++)
#pragma unroll
      for (int r = 0; r < 4; r++) {
        int row = m0 + wm * 64 + i * 16 + quad * 4 + r;
        int col = n0 + wn * 64 + j * 16 + lo;
        part[(size_t)z * PSTRIDE + (size_t)row * NGATE + col] = acc[i][j][r];
      }
}

// ---------------- hsmean: block-mean of hs fp32 -> [NBLK][HIDN] ----------------
__global__ __launch_bounds__(256) void hsmean_k(const float* __restrict__ hs, float* __restrict__ hsm) {
  int idx = blockIdx.x * 256 + threadIdx.x;   // 65536
  int n = idx >> 11, c = idx & 2047;
  const float* p = hs + (size_t)(n * BLKSZ) * HIDN + c;
  float s = 0.f;
#pragma unroll 8
  for (int r = 0; r < BLKSZ; r++) s += p[(size_t)r * HIDN];
  hsm[idx] = s * (1.0f / 64.0f);
}

__global__ __launch_bounds__(256) void kg_reduce64(const float* __restrict__ part, float* __restrict__ kg) {
  int idx = blockIdx.x * 256 + threadIdx.x;   // 65536
  float s = 0.f;
#pragma unroll
  for (int kc = 0; kc < 64; kc++) s += part[(size_t)kc * 65536 + idx];
  kg[idx] = s;
}

// ---------------- wg[(h*32+n)][r] = sum_d Wq[r][h*128+d] * kg[n][h*128+d] (fp32) ----------------
__global__ __launch_bounds__(256) void wg_k(const float* __restrict__ Wq, const float* __restrict__ kg,
                                            float* __restrict__ wg) {
  __shared__ float kl[32][128];
  int h = blockIdx.y;
  int r = blockIdx.x * 256 + threadIdx.x;
  for (int i = threadIdx.x; i < 32 * 128; i += 256)
    kl[i >> 7][i & 127] = kg[(size_t)(i >> 7) * HIDN + h * HDIM + (i & 127)];
  __syncthreads();
  float acc[32];
#pragma unroll
  for (int n = 0; n < 32; n++) acc[n] = 0.f;
  const float4* wrow = (const float4*)(Wq + (size_t)r * HIDN + h * HDIM);
  for (int d4 = 0; d4 < 32; d4++) {
    float4 w = wrow[d4];
#pragma unroll
    for (int n = 0; n < 32; n++) {
      float4 kv = *(const float4*)&kl[n][d4 * 4];
      acc[n] += w.x * kv.x + w.y * kv.y + w.z * kv.z + w.w * kv.w;
    }
  }
#pragma unroll
  for (int n = 0; n < 32; n++)
    wg[(size_t)(h * 32 + n) * HIDN + r] = acc[n];
}

// ---------------- gate + top-8 -> 32-bit block mask per (h,s) ----------------
__global__ __launch_bounds__(256) void gate_topk(const float* __restrict__ part,
                                                 unsigned* __restrict__ bsel) {
  int w = threadIdx.x >> 6, L = threadIdx.x & 63;
  int p = blockIdx.x * 4 + w;               // p = h*2048 + s
  int h = p >> 11, s = p & 2047;
  int qb = s >> 6;
  int n = L;
  float g = -1e30f;
  if (n == qb) g = 1e30f;
  else if (n < qb) {
    size_t off = (size_t)s * NGATE + h * 32 + n;
    g = part[off] + part[off + PSTRIDE] + part[off + 2 * PSTRIDE] +
        part[off + 3 * PSTRIDE] + part[off + 4 * PSTRIDE] + part[off + 5 * PSTRIDE];
  }
  int rank = 0;
#pragma unroll
  for (int j = 0; j < 32; j++) {
    float gj = __shfl(g, j, 64);
    if (gj > g || (gj == g && j < n)) rank++;
  }
  bool sel = (n <= qb) && (n < 32) && (rank < 8);
  unsigned long long bm = __ballot(sel);
  if (L == 0) bsel[p] = (unsigned)(bm & 0xffffffffull);
}

// ---------------- V^T per head: vt[h][d][s] ----------------
__global__ __launch_bounds__(256) void vtrans(const bh* __restrict__ qkv, bh* __restrict__ vt) {
  __shared__ float tile[32][33];
  int tx = threadIdx.x, ty = threadIdx.y;
  int s0 = blockIdx.x * 32, d0 = blockIdx.y * 32, h = blockIdx.z;
#pragma unroll
  for (int i = 0; i < 4; i++)
    tile[ty + i * 8][tx] = (float)qkv[(size_t)(s0 + ty + i * 8) * NQKV + 2 * HIDN + h * HDIM + d0 + tx];
  __syncthreads();
#pragma unroll
  for (int i = 0; i < 4; i++)
    vt[((size_t)h * HDIM + d0 + ty + i * 8) * SEQ + s0 + tx] = (bh)tile[tx][ty + i * 8];
}

// ---------------- attn v6: 1 workgroup (4 waves) per (h, 64-row q-block) ----------------
// dbuf K/V via global_load_lds + XOR swizzle, counted vmcnt(8) + raw s_barrier,
// per-wave block skip (16-row union), fma-folded mask, guard-free exp.
__global__ __launch_bounds__(256) void attn(const bh* __restrict__ qkv, const bh* __restrict__ vt,
                                            const unsigned* __restrict__ bsel, bh* __restrict__ obuf) {
  __shared__ __align__(16) bh Ksm[2][64 * 128];   // 2 x 16 KB, linear 256 B rows, XOR-swizzled
  __shared__ __align__(16) bh Vsm[2][128 * 64];   // 2 x 16 KB, linear 128 B rows, XOR-swizzled
  __shared__ __align__(16) bh PLb[4][16 * 72];    // bf16 P, 144 B rows (16B-aligned, 2-way banks)
  __shared__ unsigned ublk;
  const int t = threadIdx.x;
  const int w = t >> 6, L = t & 63;
  const int quad = L >> 4, lo = L & 15;
  // XCD-aware remap: bid&7 = XCD -> 2 heads per XCD (K/V ~2MB fits 4MB L2).
  // Balanced pairing: jj<32 heavy (qb 31..16, dispatched first), jj>=32 light.
  const int bid = blockIdx.x;
  const int jj = bid >> 3;
  const int h = ((bid & 7) << 1) | (jj & 1);
  const int qb = (jj < 32) ? (31 - (jj >> 1)) : ((jj - 32) >> 1);
  const int s0 = qb * 64 + w * 16;

  unsigned bs[4];
#pragma unroll
  for (int r = 0; r < 4; r++) bs[r] = bsel[h * SEQ + s0 + quad * 4 + r];
  unsigned uni = bs[0] | bs[1] | bs[2] | bs[3];
  uni |= (unsigned)__shfl_xor((int)uni, 16);
  uni |= (unsigned)__shfl_xor((int)uni, 32);
  const unsigned uniw = uni;                 // this wave's 16-row union
  if (t == 0) ublk = 0;
  __syncthreads();
  if (L == 0) atomicOr(&ublk, uni);
  __syncthreads();
  const unsigned un = ublk;                  // WG-level union (drives staging loop)

  bhx8 aq[4];
  const bh* qrow = qkv + (size_t)(s0 + lo) * NQKV + h * HDIM;
#pragma unroll
  for (int ks = 0; ks < 4; ks++) aq[ks] = *(const bhx8*)(qrow + ks * 32 + quad * 8);

  f32x4 oacc[8];
#pragma unroll
  for (int j = 0; j < 8; j++) oacc[j] = (f32x4){0.f, 0.f, 0.f, 0.f};
  f32x4 lacc = (f32x4){0.f, 0.f, 0.f, 0.f};       // row-sum accumulator (== li)
  float mi[4] = {-1e30f, -1e30f, -1e30f, -1e30f};

  bhx8 ones8;
#pragma unroll
  for (int e = 0; e < 8; e++) ones8[e] = (bh)1.0f;

  const float scale = 0.08838834764831845f;  // 1/sqrt(128)

  // stage K tile (64 rows x 256 B) + V tile (128 rows x 128 B) for block n into buffer b.
  auto stageKV = [&](int b, int n) {
    const char* ksrc = (const char*)(qkv + (size_t)(n * BLKSZ) * NQKV + HIDN + h * HDIM);
    const char* vsrc = (const char*)(vt + ((size_t)h * HDIM) * SEQ + n * BLKSZ);
    char* kb = (char*)&Ksm[b][0];
    char* vb = (char*)&Vsm[b][0];
#pragma unroll
    for (int it = 0; it < 4; it++) {
      int idx = it * 256 + t;                 // 1024 chunks of 16 B: row = idx>>4
      int row = idx >> 4, x = (idx & 15) << 4;
      GLDS16(ksrc + (size_t)row * (NQKV * 2) + (x ^ ((row & 7) << 4)),
             kb + ((idx >> 6) << 10));        // wave-uniform base; HW adds lane*16
    }
#pragma unroll
    for (int it = 0; it < 4; it++) {
      int idx = it * 256 + t;                 // 1024 chunks of 16 B: row = idx>>3
      int row = idx >> 3, x = (idx & 7) << 4;
      GLDS16(vsrc + (size_t)row * (SEQ * 2) + (x ^ ((row & 7) << 4)),
             vb + ((idx >> 6) << 10));
    }
  };

  unsigned rem = un;                          // un != 0 (self block always set)
  int ncur = (int)__builtin_ctz(rem);
  rem &= rem - 1;
  stageKV(0, ncur);
  int cur = 0;

  while (true) {
    int nnext = -1;
    if (rem) { nnext = (int)__builtin_ctz(rem); rem &= rem - 1; }
    if (nnext >= 0) {
      stageKV(cur ^ 1, nnext);
      // 8 newest outstanding = next-tile loads; wait only for current tile (+Q).
      asm volatile("s_waitcnt vmcnt(8)" ::: "memory");
    } else {
      asm volatile("s_waitcnt vmcnt(0)" ::: "memory");
    }
    __builtin_amdgcn_s_barrier();

    // per-wave skip: none of this wave's 16 rows selected block ncur ->
    // its contribution is all-masked zeros; skip compute, keep barriers.
    if ((uniw >> ncur) & 1) {
      const char* Kc = (const char*)&Ksm[cur][0];
      const char* Vc = (const char*)&Vsm[cur][0];
      const bool self = (ncur == qb);

      f32x4 sc[4];
      __builtin_amdgcn_s_setprio(1);
#pragma unroll
      for (int nt = 0; nt < 4; nt++) {
        f32x4 s4 = (f32x4){0.f, 0.f, 0.f, 0.f};
#pragma unroll
        for (int ks = 0; ks < 4; ks++) {
          const int row = nt * 16 + lo;
          bhx8 bk = *(const bhx8*)(Kc + row * 256 + ((ks * 64 + quad * 16) ^ ((row & 7) << 4)));
          s4 = __builtin_amdgcn_mfma_f32_16x16x32_bf16(aq[ks], bk, s4, 0, 0, 0);
        }
        sc[nt] = s4;
      }
      __builtin_amdgcn_s_setprio(0);

      if (self) {
#pragma unroll
        for (int nt = 0; nt < 4; nt++)
#pragma unroll
          for (int r = 0; r < 4; r++) {
            float v = sc[nt][r] * scale;
            int kpos = ncur * BLKSZ + nt * 16 + lo;
            int qpos = s0 + quad * 4 + r;
            bool ok = ((bs[r] >> ncur) & 1) && (kpos <= qpos);
            sc[nt][r] = ok ? v : -1e30f;
          }
      } else {
        float bias[4];
#pragma unroll
        for (int r = 0; r < 4; r++)
          bias[r] = ((bs[r] >> ncur) & 1) ? 0.f : -1e30f;
#pragma unroll
        for (int nt = 0; nt < 4; nt++)
#pragma unroll
          for (int r = 0; r < 4; r++)
            sc[nt][r] = sc[nt][r] * scale + bias[r];
      }
      float rm[4];
#pragma unroll
      for (int r = 0; r < 4; r++)
        rm[r] = fmaxf(fmaxf(sc[0][r], sc[1][r]), fmaxf(sc[2][r], sc[3][r]));
#pragma unroll
      for (int off = 1; off < 16; off <<= 1)
#pragma unroll
        for (int r = 0; r < 4; r++) rm[r] = fmaxf(rm[r], __shfl_xor(rm[r], off));

      // defer-max (T13, THR=8): rescale only when the running max grew enough.
      // Rows with mi still -1e30 accumulate exp(0)=1 junk until their first
      // real block arrives; that block triggers exceed for the row and
      // alpha = exp(-1e30 - real) = 0 clears oacc/lacc exactly.
      bool exceed = (rm[0] > mi[0] + 8.f) || (rm[1] > mi[1] + 8.f) ||
                    (rm[2] > mi[2] + 8.f) || (rm[3] > mi[3] + 8.f);
      if (__any(exceed)) {
        float alpha[4];
#pragma unroll
        for (int r = 0; r < 4; r++) {
          float nm = fmaxf(mi[r], rm[r]);
          alpha[r] = __expf(mi[r] - nm);
          mi[r] = nm;
        }
#pragma unroll
        for (int j = 0; j < 8; j++)
#pragma unroll
          for (int r = 0; r < 4; r++) oacc[j][r] *= alpha[r];
#pragma unroll
        for (int r = 0; r < 4; r++) lacc[r] *= alpha[r];
      }

#pragma unroll
      for (int nt = 0; nt < 4; nt++)
#pragma unroll
        for (int r = 0; r < 4; r++) {
          float pv = __expf(sc[nt][r] - mi[r]);   // masked -> exp(-1e30-mi) = 0
          PLb[w][(quad * 4 + r) * 72 + nt * 16 + lo] = (bh)pv;   // per-wave slab
        }

      __builtin_amdgcn_s_setprio(1);
#pragma unroll
      for (int kk = 0; kk < 2; kk++) {
        bhx8 pa = *(const bhx8*)&PLb[w][lo * 72 + kk * 32 + quad * 8];
        // all-ones B: every output column = row-sum of P -> lacc tracks li for free
        lacc = __builtin_amdgcn_mfma_f32_16x16x32_bf16(pa, ones8, lacc, 0, 0, 0);
#pragma unroll
        for (int j = 0; j < 8; j++) {
          const int row = j * 16 + lo;
          bhx8 vv = *(const bhx8*)(Vc + row * 128 + ((kk * 64 + quad * 16) ^ ((row & 7) << 4)));
          oacc[j] = __builtin_amdgcn_mfma_f32_16x16x32_bf16(pa, vv, oacc[j], 0, 0, 0);
        }
      }
      __builtin_amdgcn_s_setprio(0);
    }

    __builtin_amdgcn_s_barrier();   // all waves done reading buf[cur] before it is restaged
    if (nnext < 0) break;
    ncur = nnext;
    cur ^= 1;
  }

#pragma unroll
  for (int j = 0; j < 8; j++)
#pragma unroll
    for (int r = 0; r < 4; r++) {
      int row = s0 + quad * 4 + r;
      int col = h * HDIM + j * 16 + lo;
      obuf[(size_t)row * HIDN + col] = (bh)(oacc[j][r] / lacc[r]);
    }
}

// ---------------- launch ----------------
extern "C" void kernel_launch(void* const* d_in, const int* in_sizes, int n_in,
                              void* d_out, int out_size, void* d_ws, size_t ws_size,
                              hipStream_t stream) {
  const float* hs = (const float*)d_in[0];
  const float* Wq = (const float*)d_in[1];
  const float* Wk = (const float*)d_in[2];
  const float* Wv = (const float*)d_in[3];
  const float* Wo = (const float*)d_in[4];

  char* ws = (char*)d_ws;
  bh* hs_hi = (bh*)ws;            ws += (size_t)SEQ * HIDN * 2;         // 8 MB
  bh* hs_lo = (bh*)ws;            ws += (size_t)SEQ * HIDN * 2;         // 8 MB
  bh* wqkvT = (bh*)ws;            ws += (size_t)NQKV * HIDN * 2;        // 24 MB
  bh* woT = (bh*)ws;              ws += (size_t)HIDN * HIDN * 2;        // 8 MB
  bh* qkv = (bh*)ws;              ws += (size_t)SEQ * NQKV * 2;         // 24 MB
  bh* vt = (bh*)ws;               ws += (size_t)NHEAD * HDIM * SEQ * 2; // 8 MB
  bh* obuf = (bh*)ws;             ws += (size_t)SEQ * HIDN * 2;         // 8 MB
  float* hsm = (float*)ws;        ws += (size_t)NBLK * HIDN * 4;        // 256 KB
  float* kg = (float*)ws;         ws += (size_t)NBLK * HIDN * 4;        // 256 KB
  float* wg = (float*)ws;         ws += (size_t)NGATE * HIDN * 4;       // 4 MB
  bh* wg_hi = (bh*)ws;            ws += (size_t)NGATE * HIDN * 2;       // 2 MB
  bh* wg_lo = (bh*)ws;            ws += (size_t)NGATE * HIDN * 2;       // 2 MB
  unsigned* bsel = (unsigned*)ws; ws += (size_t)NHEAD * SEQ * 4;        // 128 KB
  // Total explicit: 96.6 MB.
  // Aliases (stream-serialized liveness):
  //  - kg_part (64 planes x 256 KB = 16 MB) aliases vt+obuf (contiguous 16 MB):
  //    dead until vtrans/attn, which run after kg_reduce64 consumes kg_part.
  //  - gpart (6 x 4 MB = 24 MB) aliases wqkvT: dead after the qkvkg GEMM.
  float* kg_part = (float*)vt;
  float* gpart = (float*)wqkvT;

  // hs split + fused weight transposes + block means (all depend only on inputs)
  split_f32<<<(SEQ * HIDN) / 1024, 256, 0, stream>>>(hs, hs_hi, hs_lo, SEQ * HIDN);
  transpose_cast4<<<dim3(64, 64, 4), dim3(32, 8), 0, stream>>>(Wq, Wk, Wv, Wo, wqkvT, woT);
  hsmean_k<<<(NBLK * HIDN) / 256, 256, 0, stream>>>(hs, hsm);

  // MEGA: qkv GEMM (768 blocks) + kg partial (512 blocks) co-resident
  qkvkg<<<768 + 512, 256, 0, stream>>>(hs_hi, wqkvT, qkv, hsm, Wk, kg_part);

  // fp32 gate path (wqkvT dead from here; gpart aliases it)
  kg_reduce64<<<(NBLK * HIDN) / 256, 256, 0, stream>>>(kg_part, kg);
  wg_k<<<dim3(8, NHEAD), 256, 0, stream>>>(Wq, kg, wg);
  split_f32<<<(NGATE * HIDN) / 1024, 256, 0, stream>>>(wg, wg_hi, wg_lo, NGATE * HIDN);
  gemm_gate_split<<<dim3(NGATE / 128, SEQ / 128, 6), 256, 0, stream>>>(hs_hi, hs_lo, wg_hi, wg_lo, gpart);
  gate_topk<<<(NHEAD * SEQ) / 4, 256, 0, stream>>>(gpart, bsel);

  // attention (1D grid, XCD-aware remap inside the kernel)
  vtrans<<<dim3(SEQ / 32, HDIM / 32, NHEAD), dim3(32, 8), 0, stream>>>(qkv, vt);
  attn<<<dim3(NBLK * NHEAD), 256, 0, stream>>>(qkv, vt, bsel, obuf);

  // output projection (128x128 tiles -> 256 blocks = full CU fill)
  gemm_bt128f<<<dim3(HIDN / 128, SEQ / 128), 256, 0, stream>>>(obuf, woT, (float*)d_out, SEQ, HIDN, HIDN);
}

// Round 8
// 413.186 us; speedup vs baseline: 1.4624x; 1.0191x over previous
//
#include <hip/hip_runtime.h>
#include <hip/hip_bf16.h>
#include <stdint.h>
#include <stddef.h>

// MoBA forward, MI355X.
//  split hs -> bf16 hi/lo; transpose-cast W's -> B^T bf16 (fused 4-in-1)
//  qkvkg MEGA: GEMM1 (qkv, GLDS-staged 128^2) blocks 0..767  UNION
//              kg partial (hsm @ Wk fp32, 512 latency-hiding blocks) 768..1279
//  fp32 gate path: kg_reduce64 -> wg_k v2 (LDS-staged coalesced, fused hi/lo out)
//  gate GEMM v2: virtual-K 6144 split 8 ways (K=768/slice) -> 512 blocks (2/CU)
//  gate_topk: sums 8 partial planes, rank-based top-8 -> 32-bit block mask
//  attn v7: SINGLE-buffered K/V (41.3 KB LDS -> 3 WG/CU), stage->sync->compute,
//    XOR swizzle, bf16 P, lacc ones-MFMA, defer-max, balanced qb pairing,
//    per-WAVE block skip, fma-folded mask, guard-free exp.
//  GEMM2: o @ Wo on 128^2 tiles (GLDS-staged) -> d_out fp32

using bh = __bf16;
typedef __bf16 bhx8 __attribute__((ext_vector_type(8)));
typedef __bf16 bhx4 __attribute__((ext_vector_type(4)));
typedef float  f32x4 __attribute__((ext_vector_type(4)));

#define SEQ   2048
#define HIDN  2048
#define NHEAD 16
#define HDIM  128
#define NBLK  32
#define BLKSZ 64
#define NQKV  6144
#define NGATE 512   // NBLK*NHEAD gate columns
#define LDC   136   // C-tile epilogue stride: 272 B/row = 16B-aligned, 2-way banks (free)
#define PSTRIDE ((size_t)SEQ * NGATE)   // gate partial plane stride (floats)

// global -> LDS direct copy, 16 B per lane; LDS dest = wave-uniform base + lane*16
#define GLDS16(gsrc, ldst)                                                     \
  __builtin_amdgcn_global_load_lds(                                            \
      (const __attribute__((address_space(1))) uint32_t*)(gsrc),               \
      (__attribute__((address_space(3))) uint32_t*)(ldst), 16, 0, 0)

// ---------------- split fp32 -> bf16 hi + lo ----------------
__global__ __launch_bounds__(256) void split_f32(const float* __restrict__ in,
                                                 bh* __restrict__ hi, bh* __restrict__ lo, int n) {
  int i = (blockIdx.x * 256 + threadIdx.x) * 4;
  if (i >= n) return;
  float4 v = *(const float4*)(in + i);
  bhx4 h4, l4;
  float vv[4] = {v.x, v.y, v.z, v.w};
#pragma unroll
  for (int e = 0; e < 4; e++) {
    bh h = (bh)vv[e];
    h4[e] = h;
    l4[e] = (bh)(vv[e] - (float)h);
  }
  *(bhx4*)(hi + i) = h4;
  *(bhx4*)(lo + i) = l4;
}

// ---------------- fused transpose + cast for Wq/Wk/Wv/Wo (z = which) ----------------
__global__ __launch_bounds__(256) void transpose_cast4(const float* __restrict__ Wq,
                                                       const float* __restrict__ Wk,
                                                       const float* __restrict__ Wv,
                                                       const float* __restrict__ Wo,
                                                       bh* __restrict__ wqkvT, bh* __restrict__ woT) {
  __shared__ float tile[32][33];
  const int z = blockIdx.z;
  const float* in = (z == 0) ? Wq : (z == 1) ? Wk : (z == 2) ? Wv : Wo;
  bh* out = (z < 3) ? (wqkvT + (size_t)z * HIDN * HIDN) : woT;
  int tx = threadIdx.x, ty = threadIdx.y;
  int c0 = blockIdx.x * 32, r0 = blockIdx.y * 32;
#pragma unroll
  for (int i = 0; i < 4; i++)
    tile[ty + i * 8][tx] = in[(size_t)(r0 + ty + i * 8) * HIDN + c0 + tx];
  __syncthreads();
#pragma unroll
  for (int i = 0; i < 4; i++)
    out[(size_t)(c0 + ty + i * 8) * HIDN + r0 + tx] = (bh)tile[tx][ty + i * 8];
}

// ======== shared GEMM staging: 128x128 tile, BK=64, global_load_lds ========
// LDS linear [128][64] bf16 per tile; XOR swizzle (byte ^= (row&7)<<4) applied to
// the GLOBAL source at stage time and to the ds_read byte offset (both-sides rule).
#define GEMM_STAGE_TILE(SRC, r0_, ldsbase)                                       \
  {                                                                              \
    _Pragma("unroll")                                                            \
    for (int it_ = 0; it_ < 4; it_++) {                                          \
      int idx_ = it_ * 256 + t;                                                  \
      int row_ = idx_ >> 3, x_ = (idx_ & 7) << 4;                                \
      GLDS16((const char*)(SRC) + (size_t)(r0_ + row_) * strideB + kbyte +       \
                 (x_ ^ ((row_ & 7) << 4)),                                       \
             (char*)(ldsbase) + ((idx_ >> 6) << 10));                            \
    }                                                                            \
  }

// ---------------- MEGA: qkv GEMM (blocks 0..767) UNION kg partial (768..1279) ----------------
__global__ __launch_bounds__(256) void qkvkg(const bh* __restrict__ A, const bh* __restrict__ BT,
                                             bh* __restrict__ Cb,
                                             const float* __restrict__ hsm,
                                             const float* __restrict__ Wk,
                                             float* __restrict__ part) {
  __shared__ __align__(16) char smraw[128 * LDC * 2];   // 34816 B, union of both branches
  const int t = threadIdx.x;

  if (blockIdx.x < 768) {
    // ---- qkv GEMM tile ----
    bh* smem = (bh*)smraw;
    bh* As = smem;                 // [128][64] linear, swizzled
    bh* Bs = smem + 128 * 64;
    const int L = t & 63, w = t >> 6;
    const int wm = w & 1, wn = w >> 1;
    const int quad = L >> 4, lo = L & 15;
    const int m0 = (blockIdx.x / 48) * 128, n0 = (blockIdx.x % 48) * 128;
    const size_t strideB = (size_t)HIDN * 2;

    f32x4 acc[4][4];
#pragma unroll
    for (int i = 0; i < 4; i++)
#pragma unroll
      for (int j = 0; j < 4; j++) acc[i][j] = (f32x4){0.f, 0.f, 0.f, 0.f};

    for (int k0 = 0; k0 < HIDN; k0 += 64) {
      const size_t kbyte = (size_t)k0 * 2;
      GEMM_STAGE_TILE(A, m0, As);
      GEMM_STAGE_TILE(BT, n0, Bs);
      __syncthreads();
#pragma unroll
      for (int ks = 0; ks < 2; ks++) {
        bhx8 af[4], bf_[4];
#pragma unroll
        for (int i = 0; i < 4; i++) {
          const int row = wm * 64 + i * 16 + lo;
          af[i] = *(const bhx8*)((const char*)As + row * 128 +
                                 ((ks * 64 + quad * 16) ^ ((row & 7) << 4)));
        }
#pragma unroll
        for (int j = 0; j < 4; j++) {
          const int row = wn * 64 + j * 16 + lo;
          bf_[j] = *(const bhx8*)((const char*)Bs + row * 128 +
                                  ((ks * 64 + quad * 16) ^ ((row & 7) << 4)));
        }
#pragma unroll
        for (int i = 0; i < 4; i++)
#pragma unroll
          for (int j = 0; j < 4; j++)
            acc[i][j] = __builtin_amdgcn_mfma_f32_16x16x32_bf16(af[i], bf_[j], acc[i][j], 0, 0, 0);
      }
      __syncthreads();
    }

    // epilogue: scatter acc -> LDS C-tile, then fully-coalesced 16B global stores
    bh* Cs = smem;
#pragma unroll
    for (int i = 0; i < 4; i++)
#pragma unroll
      for (int j = 0; j < 4; j++)
#pragma unroll
        for (int r = 0; r < 4; r++)
          Cs[(wm * 64 + i * 16 + quad * 4 + r) * LDC + wn * 64 + j * 16 + lo] = (bh)acc[i][j][r];
    __syncthreads();
#pragma unroll
    for (int it = 0; it < 8; it++) {
      int idx = it * 256 + t;                 // 2048 chunks: 128 rows x 16
      int row = idx >> 4, cg = idx & 15;
      *(uint4*)(Cb + (size_t)(m0 + row) * NQKV + n0 + cg * 8) = *(const uint4*)&Cs[row * LDC + cg * 8];
    }
  } else {
    // ---- kg partial: 512 blocks (8 c-chunks x 64 k-chunks), high occupancy ----
    float (*hl)[32] = (float (*)[32])smraw;   // hsm[32 n][32 k] slice, 4 KB
    const int b2 = blockIdx.x - 768;
    const int c = (b2 & 7) * 256 + t;
    const int ky = b2 >> 3;
    const int k0 = ky * 32;
    for (int i = t; i < 32 * 32; i += 256)
      hl[i >> 5][i & 31] = hsm[(size_t)(i >> 5) * HIDN + k0 + (i & 31)];
    __syncthreads();
    float acc[32];
#pragma unroll
    for (int n = 0; n < 32; n++) acc[n] = 0.f;
#pragma unroll 2
    for (int k4 = 0; k4 < 8; k4++) {
      float w0 = Wk[(size_t)(k0 + k4 * 4 + 0) * HIDN + c];
      float w1 = Wk[(size_t)(k0 + k4 * 4 + 1) * HIDN + c];
      float w2 = Wk[(size_t)(k0 + k4 * 4 + 2) * HIDN + c];
      float w3 = Wk[(size_t)(k0 + k4 * 4 + 3) * HIDN + c];
#pragma unroll
      for (int n = 0; n < 32; n++) {
        float4 hv = *(const float4*)&hl[n][k4 * 4];
        acc[n] += hv.x * w0 + hv.y * w1 + hv.z * w2 + hv.w * w3;
      }
    }
#pragma unroll
    for (int n = 0; n < 32; n++)
      part[((size_t)ky * 32 + n) * HIDN + c] = acc[n];
  }
}

// ---------------- GEMM: 128^2 tile, fp32 out (o-projection) ----------------
__global__ __launch_bounds__(256) void gemm_bt128f(const bh* __restrict__ A, const bh* __restrict__ BT,
                                                   float* __restrict__ Cf, int M, int N, int K) {
  __shared__ __align__(16) bh smem[2 * 128 * 64];  // 32 KB
  bh* As = smem;
  bh* Bs = smem + 128 * 64;
  const int t = threadIdx.x;
  const int L = t & 63, w = t >> 6;
  const int wm = w & 1, wn = w >> 1;
  const int quad = L >> 4, lo = L & 15;
  const int m0 = blockIdx.y * 128, n0 = blockIdx.x * 128;
  const size_t strideB = (size_t)K * 2;

  f32x4 acc[4][4];
#pragma unroll
  for (int i = 0; i < 4; i++)
#pragma unroll
    for (int j = 0; j < 4; j++) acc[i][j] = (f32x4){0.f, 0.f, 0.f, 0.f};

  for (int k0 = 0; k0 < K; k0 += 64) {
    const size_t kbyte = (size_t)k0 * 2;
    GEMM_STAGE_TILE(A, m0, As);
    GEMM_STAGE_TILE(BT, n0, Bs);
    __syncthreads();
#pragma unroll
    for (int ks = 0; ks < 2; ks++) {
      bhx8 af[4], bf_[4];
#pragma unroll
      for (int i = 0; i < 4; i++) {
        const int row = wm * 64 + i * 16 + lo;
        af[i] = *(const bhx8*)((const char*)As + row * 128 +
                               ((ks * 64 + quad * 16) ^ ((row & 7) << 4)));
      }
#pragma unroll
      for (int j = 0; j < 4; j++) {
        const int row = wn * 64 + j * 16 + lo;
        bf_[j] = *(const bhx8*)((const char*)Bs + row * 128 +
                                ((ks * 64 + quad * 16) ^ ((row & 7) << 4)));
      }
#pragma unroll
      for (int i = 0; i < 4; i++)
#pragma unroll
        for (int j = 0; j < 4; j++)
          acc[i][j] = __builtin_amdgcn_mfma_f32_16x16x32_bf16(af[i], bf_[j], acc[i][j], 0, 0, 0);
    }
    __syncthreads();
  }

  // fp32 stores: 16 lanes x 4 B = full 64 B sectors per quad-row (no amplification)
#pragma unroll
  for (int i = 0; i < 4; i++)
#pragma unroll
    for (int j = 0; j < 4; j++)
#pragma unroll
      for (int r = 0; r < 4; r++) {
        int row = m0 + wm * 64 + i * 16 + quad * 4 + r;
        int col = n0 + wn * 64 + j * 16 + lo;
        Cf[(size_t)row * N + col] = acc[i][j][r];
      }
}

// ---------------- gate GEMM v2: virtual K=6144 (3 phases concat), 8 slices ----------------
// vk in [0,2048): hs_hi @ wg_hi; [2048,4096): hs_lo @ wg_hi; [4096,6144): hs_hi @ wg_lo.
// z slice handles vk in [z*768, (z+1)*768); phase uniform per 64-step (768*z % 64 == 0).
__global__ __launch_bounds__(256) void gemm_gate_split(const bh* __restrict__ hs_hi,
                                                       const bh* __restrict__ hs_lo,
                                                       const bh* __restrict__ wg_hi,
                                                       const bh* __restrict__ wg_lo,
                                                       float* __restrict__ part6,
                                                       float* __restrict__ part2) {
  __shared__ __align__(16) bh smem[2 * 128 * 64];  // 32 KB
  bh* As = smem;
  bh* Bs = smem + 128 * 64;
  const int t = threadIdx.x;
  const int L = t & 63, w = t >> 6;
  const int wm = w & 1, wn = w >> 1;
  const int quad = L >> 4, lo = L & 15;
  const int m0 = blockIdx.y * 128, n0 = blockIdx.x * 128;
  const int z = blockIdx.z;
  const size_t strideB = (size_t)HIDN * 2;

  f32x4 acc[4][4];
#pragma unroll
  for (int i = 0; i < 4; i++)
#pragma unroll
    for (int j = 0; j < 4; j++) acc[i][j] = (f32x4){0.f, 0.f, 0.f, 0.f};

  for (int k0 = 0; k0 < 768; k0 += 64) {
    const int vk = z * 768 + k0;
    const int ph = vk >> 11;                 // 0,1,2
    const bh* Ap = (ph == 1) ? hs_lo : hs_hi;
    const bh* Bp = (ph == 2) ? wg_lo : wg_hi;
    const size_t kbyte = (size_t)(vk & 2047) * 2;
    GEMM_STAGE_TILE(Ap, m0, As);
    GEMM_STAGE_TILE(Bp, n0, Bs);
    __syncthreads();
#pragma unroll
    for (int ks = 0; ks < 2; ks++) {
      bhx8 af[4], bf_[4];
#pragma unroll
      for (int i = 0; i < 4; i++) {
        const int row = wm * 64 + i * 16 + lo;
        af[i] = *(const bhx8*)((const char*)As + row * 128 +
                               ((ks * 64 + quad * 16) ^ ((row & 7) << 4)));
      }
#pragma unroll
      for (int j = 0; j < 4; j++) {
        const int row = wn * 64 + j * 16 + lo;
        bf_[j] = *(const bhx8*)((const char*)Bs + row * 128 +
                                ((ks * 64 + quad * 16) ^ ((row & 7) << 4)));
      }
#pragma unroll
      for (int i = 0; i < 4; i++)
#pragma unroll
        for (int j = 0; j < 4; j++)
          acc[i][j] = __builtin_amdgcn_mfma_f32_16x16x32_bf16(af[i], bf_[j], acc[i][j], 0, 0, 0);
    }
    __syncthreads();
  }

  float* outp = (z < 6) ? (part6 + (size_t)z * PSTRIDE) : (part2 + (size_t)(z - 6) * PSTRIDE);
#pragma unroll
  for (int i = 0; i < 4; i++)
#pragma unroll
    for (int j = 0; j < 4; j++)
#pragma unroll
      for (int r = 0; r < 4; r++) {
        int row = m0 + wm * 64 + i * 16 + quad * 4 + r;
        int col = n0 + wn * 64 + j * 16 + lo;
        outp[(size_t)row * NGATE + col] = acc[i][j][r];
      }
}

// ---------------- hsmean: block-mean of hs fp32 -> [NBLK][HIDN] ----------------
__global__ __launch_bounds__(256) void hsmean_k(const float* __restrict__ hs, float* __restrict__ hsm) {
  int idx = blockIdx.x * 256 + threadIdx.x;   // 65536
  int n = idx >> 11, c = idx & 2047;
  const float* p = hs + (size_t)(n * BLKSZ) * HIDN + c;
  float s = 0.f;
#pragma unroll 8
  for (int r = 0; r < BLKSZ; r++) s += p[(size_t)r * HIDN];
  hsm[idx] = s * (1.0f / 64.0f);
}

__global__ __launch_bounds__(256) void kg_reduce64(const float* __restrict__ part, float* __restrict__ kg) {
  int idx = blockIdx.x * 256 + threadIdx.x;   // 65536
  float s = 0.f;
#pragma unroll
  for (int kc = 0; kc < 64; kc++) s += part[(size_t)kc * 65536 + idx];
  kg[idx] = s;
}

// ---------------- wg_k v2: LDS-staged coalesced, fused bf16 hi/lo output ----------------
// wg[(h*32+n)][r] = sum_d Wq[r][h*128+d] * kg[n][h*128+d] (fp32 accum).
__global__ __launch_bounds__(256) void wg_k(const float* __restrict__ Wq, const float* __restrict__ kg,
                                            bh* __restrict__ wg_hi, bh* __restrict__ wg_lo) {
  __shared__ float wst[128][65];   // Wq tile transposed [d][r], padded: 33.3 KB
  __shared__ float kl[32][129];    // kg slice [n][d], padded: 16.5 KB
  const int h = blockIdx.y;
  const int r0 = blockIdx.x * 256;
  const int t = threadIdx.x;
  const int rloc = t & 63, ng = t >> 6;      // 4 n-groups of 8

  for (int i = t; i < 32 * 128; i += 256)
    kl[i >> 7][i & 127] = kg[(size_t)(i >> 7) * HIDN + h * HDIM + (i & 127)];

#pragma unroll
  for (int rt = 0; rt < 4; rt++) {
    __syncthreads();                          // protect wst from prior tile's readers
    for (int i = t; i < 64 * 128; i += 256) {
      int row = i >> 7, col = i & 127;        // coalesced global read, conflict-free LDS write
      wst[col][row] = Wq[(size_t)(r0 + rt * 64 + row) * HIDN + h * HDIM + col];
    }
    __syncthreads();
    float acc8[8];
#pragma unroll
    for (int nn = 0; nn < 8; nn++) acc8[nn] = 0.f;
    for (int d = 0; d < 128; d++) {
      float wv = wst[d][rloc];                // lanes consecutive -> conflict-free
#pragma unroll
      for (int nn = 0; nn < 8; nn++)
        acc8[nn] += wv * kl[ng * 8 + nn][d];  // broadcast within 16-lane group
    }
#pragma unroll
    for (int nn = 0; nn < 8; nn++) {
      int n = ng * 8 + nn;
      float v = acc8[nn];
      bh hi = (bh)v;
      size_t off = (size_t)(h * 32 + n) * HIDN + r0 + rt * 64 + rloc;
      wg_hi[off] = hi;
      wg_lo[off] = (bh)(v - (float)hi);
    }
  }
}

// ---------------- gate + top-8 -> 32-bit block mask per (h,s) ----------------
__global__ __launch_bounds__(256) void gate_topk(const float* __restrict__ part6,
                                                 const float* __restrict__ part2,
                                                 unsigned* __restrict__ bsel) {
  int w = threadIdx.x >> 6, L = threadIdx.x & 63;
  int p = blockIdx.x * 4 + w;               // p = h*2048 + s
  int h = p >> 11, s = p & 2047;
  int qb = s >> 6;
  int n = L;
  float g = -1e30f;
  if (n == qb) g = 1e30f;
  else if (n < qb) {
    size_t off = (size_t)s * NGATE + h * 32 + n;
    g = part6[off] + part6[off + PSTRIDE] + part6[off + 2 * PSTRIDE] +
        part6[off + 3 * PSTRIDE] + part6[off + 4 * PSTRIDE] + part6[off + 5 * PSTRIDE] +
        part2[off] + part2[off + PSTRIDE];
  }
  int rank = 0;
#pragma unroll
  for (int j = 0; j < 32; j++) {
    float gj = __shfl(g, j, 64);
    if (gj > g || (gj == g && j < n)) rank++;
  }
  bool sel = (n <= qb) && (n < 32) && (rank < 8);
  unsigned long long bm = __ballot(sel);
  if (L == 0) bsel[p] = (unsigned)(bm & 0xffffffffull);
}

// ---------------- V^T per head: vt[h][d][s] ----------------
__global__ __launch_bounds__(256) void vtrans(const bh* __restrict__ qkv, bh* __restrict__ vt) {
  __shared__ float tile[32][33];
  int tx = threadIdx.x, ty = threadIdx.y;
  int s0 = blockIdx.x * 32, d0 = blockIdx.y * 32, h = blockIdx.z;
#pragma unroll
  for (int i = 0; i < 4; i++)
    tile[ty + i * 8][tx] = (float)qkv[(size_t)(s0 + ty + i * 8) * NQKV + 2 * HIDN + h * HDIM + d0 + tx];
  __syncthreads();
#pragma unroll
  for (int i = 0; i < 4; i++)
    vt[((size_t)h * HDIM + d0 + ty + i * 8) * SEQ + s0 + tx] = (bh)tile[tx][ty + i * 8];
}

// ---------------- attn v7: 1 WG (4 waves) per (h, 64-row q-block), 3 WG/CU ----------------
// SINGLE-buffered K/V (41.3 KB LDS): stage -> __syncthreads (drains vmcnt) ->
// compute -> __syncthreads. Latency hidden by 3 co-resident WGs per CU.
__global__ __launch_bounds__(256) void attn(const bh* __restrict__ qkv, const bh* __restrict__ vt,
                                            const unsigned* __restrict__ bsel, bh* __restrict__ obuf) {
  __shared__ __align__(16) bh Ksm[64 * 128];      // 16 KB, linear 256 B rows, XOR-swizzled
  __shared__ __align__(16) bh Vsm[128 * 64];      // 16 KB, linear 128 B rows, XOR-swizzled
  __shared__ __align__(16) bh PLb[4][16 * 72];    // bf16 P, 144 B rows
  __shared__ unsigned ublk;
  const int t = threadIdx.x;
  const int w = t >> 6, L = t & 63;
  const int quad = L >> 4, lo = L & 15;
  // XCD-aware remap: bid&7 = XCD -> 2 heads per XCD (K/V ~2MB fits 4MB L2).
  // Balanced pairing: jj<32 heavy (qb 31..16, dispatched first), jj>=32 light.
  const int bid = blockIdx.x;
  const int jj = bid >> 3;
  const int h = ((bid & 7) << 1) | (jj & 1);
  const int qb = (jj < 32) ? (31 - (jj >> 1)) : ((jj - 32) >> 1);
  const int s0 = qb * 64 + w * 16;

  unsigned bs[4];
#pragma unroll
  for (int r = 0; r < 4; r++) bs[r] = bsel[h * SEQ + s0 + quad * 4 + r];
  unsigned uni = bs[0] | bs[1] | bs[2] | bs[3];
  uni |= (unsigned)__shfl_xor((int)uni, 16);
  uni |= (unsigned)__shfl_xor((int)uni, 32);
  const unsigned uniw = uni;                 // this wave's 16-row union
  if (t == 0) ublk = 0;
  __syncthreads();
  if (L == 0) atomicOr(&ublk, uni);
  __syncthreads();
  const unsigned un = ublk;                  // WG-level union (drives staging loop)

  bhx8 aq[4];
  const bh* qrow = qkv + (size_t)(s0 + lo) * NQKV + h * HDIM;
#pragma unroll
  for (int ks = 0; ks < 4; ks++) aq[ks] = *(const bhx8*)(qrow + ks * 32 + quad * 8);

  f32x4 oacc[8];
#pragma unroll
  for (int j = 0; j < 8; j++) oacc[j] = (f32x4){0.f, 0.f, 0.f, 0.f};
  f32x4 lacc = (f32x4){0.f, 0.f, 0.f, 0.f};       // row-sum accumulator (== li)
  float mi[4] = {-1e30f, -1e30f, -1e30f, -1e30f};

  bhx8 ones8;
#pragma unroll
  for (int e = 0; e < 8; e++) ones8[e] = (bh)1.0f;

  const float scale = 0.08838834764831845f;  // 1/sqrt(128)

  unsigned rem = un;                          // un != 0 (self block always set)
  while (rem) {
    const int ncur = (int)__builtin_ctz(rem);
    rem &= rem - 1;

    // stage K tile (64 rows x 256 B) + V tile (128 rows x 128 B) for block ncur.
    {
      const char* ksrc = (const char*)(qkv + (size_t)(ncur * BLKSZ) * NQKV + HIDN + h * HDIM);
      const char* vsrc = (const char*)(vt + ((size_t)h * HDIM) * SEQ + ncur * BLKSZ);
#pragma unroll
      for (int it = 0; it < 4; it++) {
        int idx = it * 256 + t;               // 1024 chunks of 16 B: row = idx>>4
        int row = idx >> 4, x = (idx & 15) << 4;
        GLDS16(ksrc + (size_t)row * (NQKV * 2) + (x ^ ((row & 7) << 4)),
               (char*)Ksm + ((idx >> 6) << 10));   // wave-uniform base; HW adds lane*16
      }
#pragma unroll
      for (int it = 0; it < 4; it++) {
        int idx = it * 256 + t;               // 1024 chunks of 16 B: row = idx>>3
        int row = idx >> 3, x = (idx & 7) << 4;
        GLDS16(vsrc + (size_t)row * (SEQ * 2) + (x ^ ((row & 7) << 4)),
               (char*)Vsm + ((idx >> 6) << 10));
      }
    }
    __syncthreads();   // drains vmcnt(0); tile ready

    // per-wave skip: none of this wave's 16 rows selected block ncur ->
    // its contribution is all-masked zeros; skip compute, keep barriers.
    if ((uniw >> ncur) & 1) {
      const char* Kc = (const char*)Ksm;
      const char* Vc = (const char*)Vsm;
      const bool self = (ncur == qb);

      f32x4 sc[4];
      __builtin_amdgcn_s_setprio(1);
#pragma unroll
      for (int nt = 0; nt < 4; nt++) {
        f32x4 s4 = (f32x4){0.f, 0.f, 0.f, 0.f};
#pragma unroll
        for (int ks = 0; ks < 4; ks++) {
          const int row = nt * 16 + lo;
          bhx8 bk = *(const bhx8*)(Kc + row * 256 + ((ks * 64 + quad * 16) ^ ((row & 7) << 4)));
          s4 = __builtin_amdgcn_mfma_f32_16x16x32_bf16(aq[ks], bk, s4, 0, 0, 0);
        }
        sc[nt] = s4;
      }
      __builtin_amdgcn_s_setprio(0);

      if (self) {
#pragma unroll
        for (int nt = 0; nt < 4; nt++)
#pragma unroll
          for (int r = 0; r < 4; r++) {
            float v = sc[nt][r] * scale;
            int kpos = ncur * BLKSZ + nt * 16 + lo;
            int qpos = s0 + quad * 4 + r;
            bool ok = ((bs[r] >> ncur) & 1) && (kpos <= qpos);
            sc[nt][r] = ok ? v : -1e30f;
          }
      } else {
        float bias[4];
#pragma unroll
        for (int r = 0; r < 4; r++)
          bias[r] = ((bs[r] >> ncur) & 1) ? 0.f : -1e30f;
#pragma unroll
        for (int nt = 0; nt < 4; nt++)
#pragma unroll
          for (int r = 0; r < 4; r++)
            sc[nt][r] = sc[nt][r] * scale + bias[r];
      }
      float rm[4];
#pragma unroll
      for (int r = 0; r < 4; r++)
        rm[r] = fmaxf(fmaxf(sc[0][r], sc[1][r]), fmaxf(sc[2][r], sc[3][r]));
#pragma unroll
      for (int off = 1; off < 16; off <<= 1)
#pragma unroll
        for (int r = 0; r < 4; r++) rm[r] = fmaxf(rm[r], __shfl_xor(rm[r], off));

      // defer-max (T13, THR=8); rows with mi=-1e30 accumulate exp(0)=1 junk until
      // their first real block triggers exceed and alpha=0 clears oacc/lacc exactly.
      bool exceed = (rm[0] > mi[0] + 8.f) || (rm[1] > mi[1] + 8.f) ||
                    (rm[2] > mi[2] + 8.f) || (rm[3] > mi[3] + 8.f);
      if (__any(exceed)) {
        float alpha[4];
#pragma unroll
        for (int r = 0; r < 4; r++) {
          float nm = fmaxf(mi[r], rm[r]);
          alpha[r] = __expf(mi[r] - nm);
          mi[r] = nm;
        }
#pragma unroll
        for (int j = 0; j < 8; j++)
#pragma unroll
          for (int r = 0; r < 4; r++) oacc[j][r] *= alpha[r];
#pragma unroll
        for (int r = 0; r < 4; r++) lacc[r] *= alpha[r];
      }

#pragma unroll
      for (int nt = 0; nt < 4; nt++)
#pragma unroll
        for (int r = 0; r < 4; r++) {
          float pv = __expf(sc[nt][r] - mi[r]);   // masked -> exp(-1e30-mi) = 0
          PLb[w][(quad * 4 + r) * 72 + nt * 16 + lo] = (bh)pv;   // per-wave slab
        }

      __builtin_amdgcn_s_setprio(1);
#pragma unroll
      for (int kk = 0; kk < 2; kk++) {
        bhx8 pa = *(const bhx8*)&PLb[w][lo * 72 + kk * 32 + quad * 8];
        // all-ones B: every output column = row-sum of P -> lacc tracks li for free
        lacc = __builtin_amdgcn_mfma_f32_16x16x32_bf16(pa, ones8, lacc, 0, 0, 0);
#pragma unroll
        for (int j = 0; j < 8; j++) {
          const int row = j * 16 + lo;
          bhx8 vv = *(const bhx8*)(Vc + row * 128 + ((kk * 64 + quad * 16) ^ ((row & 7) << 4)));
          oacc[j] = __builtin_amdgcn_mfma_f32_16x16x32_bf16(pa, vv, oacc[j], 0, 0, 0);
        }
      }
      __builtin_amdgcn_s_setprio(0);
    }

    __syncthreads();   // all waves done reading Ksm/Vsm before restage
  }

#pragma unroll
  for (int j = 0; j < 8; j++)
#pragma unroll
    for (int r = 0; r < 4; r++) {
      int row = s0 + quad * 4 + r;
      int col = h * HDIM + j * 16 + lo;
      obuf[(size_t)row * HIDN + col] = (bh)(oacc[j][r] / lacc[r]);
    }
}

// ---------------- launch ----------------
extern "C" void kernel_launch(void* const* d_in, const int* in_sizes, int n_in,
                              void* d_out, int out_size, void* d_ws, size_t ws_size,
                              hipStream_t stream) {
  const float* hs = (const float*)d_in[0];
  const float* Wq = (const float*)d_in[1];
  const float* Wk = (const float*)d_in[2];
  const float* Wv = (const float*)d_in[3];
  const float* Wo = (const float*)d_in[4];

  char* ws = (char*)d_ws;
  bh* hs_hi = (bh*)ws;            ws += (size_t)SEQ * HIDN * 2;         // 8 MB
  bh* hs_lo = (bh*)ws;            ws += (size_t)SEQ * HIDN * 2;         // 8 MB
  bh* wqkvT = (bh*)ws;            ws += (size_t)NQKV * HIDN * 2;        // 24 MB
  bh* woT = (bh*)ws;              ws += (size_t)HIDN * HIDN * 2;        // 8 MB
  bh* qkv = (bh*)ws;              ws += (size_t)SEQ * NQKV * 2;         // 24 MB
  bh* vt = (bh*)ws;               ws += (size_t)NHEAD * HDIM * SEQ * 2; // 8 MB
  bh* obuf = (bh*)ws;             ws += (size_t)SEQ * HIDN * 2;         // 8 MB
  float* hsm = (float*)ws;        ws += (size_t)NBLK * HIDN * 4;        // 256 KB
  float* kg = (float*)ws;         ws += (size_t)NBLK * HIDN * 4;        // 256 KB
  bh* wg_hi = (bh*)ws;            ws += (size_t)NGATE * HIDN * 2;       // 2 MB
  bh* wg_lo = (bh*)ws;            ws += (size_t)NGATE * HIDN * 2;       // 2 MB
  unsigned* bsel = (unsigned*)ws; ws += (size_t)NHEAD * SEQ * 4;        // 128 KB
  // Total explicit: 92.6 MB.
  // Aliases (stream-serialized liveness):
  //  - kg_part (64 planes x 256 KB = 16 MB) aliases vt+obuf: dead until
  //    vtrans/attn; consumed by kg_reduce64 before gate gemm reuses vt.
  //  - gate planes 0..5 (24 MB) alias wqkvT (dead after qkvkg GEMM);
  //    planes 6..7 (8 MB) alias vt (kg_part consumed; vtrans runs after topk).
  float* kg_part = (float*)vt;
  float* gpart6 = (float*)wqkvT;
  float* gpart2 = (float*)vt;

  // hs split + fused weight transposes + block means (depend only on inputs)
  split_f32<<<(SEQ * HIDN) / 1024, 256, 0, stream>>>(hs, hs_hi, hs_lo, SEQ * HIDN);
  transpose_cast4<<<dim3(64, 64, 4), dim3(32, 8), 0, stream>>>(Wq, Wk, Wv, Wo, wqkvT, woT);
  hsmean_k<<<(NBLK * HIDN) / 256, 256, 0, stream>>>(hs, hsm);

  // MEGA: qkv GEMM (768 blocks) + kg partial (512 blocks) co-resident
  qkvkg<<<768 + 512, 256, 0, stream>>>(hs_hi, wqkvT, qkv, hsm, Wk, kg_part);

  // fp32 gate path (wqkvT dead from here)
  kg_reduce64<<<(NBLK * HIDN) / 256, 256, 0, stream>>>(kg_part, kg);
  wg_k<<<dim3(8, NHEAD), 256, 0, stream>>>(Wq, kg, wg_hi, wg_lo);
  gemm_gate_split<<<dim3(NGATE / 128, SEQ / 128, 8), 256, 0, stream>>>(
      hs_hi, hs_lo, wg_hi, wg_lo, gpart6, gpart2);
  gate_topk<<<(NHEAD * SEQ) / 4, 256, 0, stream>>>(gpart6, gpart2, bsel);

  // attention (1D grid, XCD-aware remap inside the kernel)
  vtrans<<<dim3(SEQ / 32, HDIM / 32, NHEAD), dim3(32, 8), 0, stream>>>(qkv, vt);
  attn<<<dim3(NBLK * NHEAD), 256, 0, stream>>>(qkv, vt, bsel, obuf);

  // output projection (128x128 tiles -> 256 blocks)
  gemm_bt128f<<<dim3(HIDN / 128, SEQ / 128), 256, 0, stream>>>(obuf, woT, (float*)d_out, SEQ, HIDN, HIDN);
}